// Round 14
// baseline (275.827 us; speedup 1.0000x reference)
//
#include <hip/hip_runtime.h>

typedef __attribute__((ext_vector_type(8))) short bf16x8;
typedef __attribute__((ext_vector_type(4))) float f32x4;
typedef __attribute__((ext_vector_type(2))) float f32x2;

__device__ __forceinline__ unsigned short f2bf(float x) {
    union { float f; unsigned u; } v; v.f = x;
    unsigned r = v.u + 0x7FFFu + ((v.u >> 16) & 1u);
    return (unsigned short)(r >> 16);
}
__device__ __forceinline__ float bf2f(unsigned u) {
    union { unsigned u; float f; } v; v.u = u << 16;
    return v.f;
}
__device__ __forceinline__ unsigned char f2fp8(float x) {
    return (unsigned char)(__builtin_amdgcn_cvt_pk_fp8_f32(x, x, 0, false) & 0xff);
}

#define CHUNK 4096
#define CAP 4608

// ---------- K1: weight transpose + zero bcursor ----------
__global__ __launch_bounds__(256) void k_wt(
    const float* __restrict__ Ws0, const float* __restrict__ Wn0,
    const float* __restrict__ Ws1, const float* __restrict__ Wn1,
    const float* __restrict__ Ws2, const float* __restrict__ Wn2,
    unsigned short* __restrict__ WT0s, unsigned short* __restrict__ WT0n,
    unsigned short* __restrict__ WT1s, unsigned short* __restrict__ WT1n,
    unsigned short* __restrict__ WT2, int* __restrict__ bcursor) {
    int tid = threadIdx.x;
    if (blockIdx.x == 0) bcursor[tid] = 0;
    int i = blockIdx.x * 256 + tid;
    if (i < 16384)      { int j = i;         WT0s[j] = f2bf(Ws0[(j & 127) * 128 + (j >> 7)]); }
    else if (i < 32768) { int j = i - 16384; WT0n[j] = f2bf(Wn0[(j & 127) * 128 + (j >> 7)]); }
    else if (i < 49152) { int j = i - 32768; WT1s[j] = f2bf(Ws1[(j & 127) * 128 + (j >> 7)]); }
    else if (i < 65536) { int j = i - 49152; WT1n[j] = f2bf(Wn1[(j & 127) * 128 + (j >> 7)]); }
    else if (i < 73728) { int j = i - 65536; WT2[j] = f2bf(Ws2[(j & 127) * 64 + (j >> 7)]); }
    else if (i < 81920) { int j = i - 73728; WT2[8192 + j] = f2bf(Wn2[(j & 127) * 64 + (j >> 7)]); }
}

// ---------- K2: bucket scatter (blocks < ech) UNION layer-0 GEMM ----------
// T8 layout (layers 0/1): [2 col-halves][N][64] fp8 bytes
__global__ __launch_bounds__(256) void k_scatter_gemm0(
    const int* __restrict__ esrc, const int* __restrict__ edst,
    int* __restrict__ bcursor, unsigned* __restrict__ bsorted, int E, int ech,
    const float* __restrict__ Xf,
    const unsigned short* __restrict__ WsT, const unsigned short* __restrict__ WnT,
    const float* __restrict__ bias, unsigned short* __restrict__ Ab,
    unsigned char* __restrict__ T8, int N) {
    __shared__ uint4 smem[1216];
    int tid = threadIdx.x;
    if ((int)blockIdx.x < ech) {
        unsigned* stage = (unsigned*)smem;
        int* hist = (int*)(stage + CHUNK);
        int* base = hist + 256;
        int* cur  = base + 256;
        hist[tid] = 0;
        __syncthreads();
        int e0 = blockIdx.x * CHUNK;
        int cnt = min(CHUNK, E - e0);
        for (int i = tid; i < cnt; i += 256) {
            int d = edst[e0 + i], s = esrc[e0 + i];
            stage[i] = ((unsigned)d << 16) | (unsigned)s;
            atomicAdd(&hist[d >> 8], 1);
        }
        __syncthreads();
        int h = hist[tid];
        base[tid] = h ? (tid * CAP + atomicAdd(&bcursor[tid], h)) : 0;
        cur[tid] = 0;
        __syncthreads();
        for (int i = tid; i < cnt; i += 256) {
            unsigned pk = stage[i];
            int b = pk >> 24;
            int p = base[b] + atomicAdd(&cur[b], 1);
            bsorted[p] = pk;
        }
    } else {
        unsigned short (*xs)[136] = (unsigned short(*)[136])smem;
        int br = (blockIdx.x - ech) << 6;
        #pragma unroll
        for (int it = 0; it < 4; ++it) {
            int idx = tid + it * 256;
            int row = idx >> 4;
            int co = (idx & 15) << 3;
            int n = br + row;
            uint4 pk = make_uint4(0, 0, 0, 0);
            if (n < N) {
                float4 v0 = *(const float4*)(Xf + (size_t)n * 128 + co);
                float4 v1 = *(const float4*)(Xf + (size_t)n * 128 + co + 4);
                pk.x = (unsigned)f2bf(v0.x) | ((unsigned)f2bf(v0.y) << 16);
                pk.y = (unsigned)f2bf(v0.z) | ((unsigned)f2bf(v0.w) << 16);
                pk.z = (unsigned)f2bf(v1.x) | ((unsigned)f2bf(v1.y) << 16);
                pk.w = (unsigned)f2bf(v1.z) | ((unsigned)f2bf(v1.w) << 16);
            }
            *(uint4*)&xs[row][co] = pk;
        }
        __syncthreads();
        int wave = tid >> 6;
        int lane = tid & 63;
        int lrow = lane & 15;
        int kg = lane >> 4;
        int colbase = wave << 5;
        f32x4 acc[4][2][2];
        #pragma unroll
        for (int r = 0; r < 4; ++r)
            #pragma unroll
            for (int c = 0; c < 2; ++c) {
                acc[r][c][0] = (f32x4){0.f, 0.f, 0.f, 0.f};
                acc[r][c][1] = (f32x4){0.f, 0.f, 0.f, 0.f};
            }
        #pragma unroll
        for (int ks = 0; ks < 4; ++ks) {
            int kb = ks * 32 + kg * 8;
            bf16x8 af[4];
            #pragma unroll
            for (int r = 0; r < 4; ++r) af[r] = *(const bf16x8*)&xs[r * 16 + lrow][kb];
            bf16x8 bS[2], bN[2];
            #pragma unroll
            for (int c = 0; c < 2; ++c) {
                int col = colbase + c * 16 + lrow;
                bS[c] = *(const bf16x8*)(WsT + (size_t)col * 128 + kb);
                bN[c] = *(const bf16x8*)(WnT + (size_t)col * 128 + kb);
            }
            #pragma unroll
            for (int r = 0; r < 4; ++r)
                #pragma unroll
                for (int c = 0; c < 2; ++c) {
                    acc[r][c][0] = __builtin_amdgcn_mfma_f32_16x16x32_bf16(af[r], bS[c], acc[r][c][0], 0, 0, 0);
                    acc[r][c][1] = __builtin_amdgcn_mfma_f32_16x16x32_bf16(af[r], bN[c], acc[r][c][1], 0, 0, 0);
                }
        }
        #pragma unroll
        for (int r = 0; r < 4; ++r)
            #pragma unroll
            for (int c = 0; c < 2; ++c) {
                int col = colbase + c * 16 + lrow;
                float bv = bias[col];
                int hh = col >> 6, cl = col & 63;
                #pragma unroll
                for (int q = 0; q < 4; ++q) {
                    int n = br + r * 16 + kg * 4 + q;
                    if (n < N) {
                        Ab[(size_t)n * 128 + col] = f2bf(acc[r][c][0][q] + bv);
                        T8[((size_t)hh * N + n) * 64 + cl] = f2fp8(acc[r][c][1][q]);
                    }
                }
            }
    }
}

// ---------- K3: per-bucket CSR finalize; csr = src<<6 (byte offset within a 64B-row plane) ----------
__global__ __launch_bounds__(256) void k_bucket_csr(const unsigned* __restrict__ bsorted,
                                                    const int* __restrict__ bcursor,
                                                    int2* __restrict__ rbe,
                                                    float* __restrict__ dinv,
                                                    int* __restrict__ csr, int N) {
    __shared__ int sh[256];
    __shared__ int cur[256];
    int tid = threadIdx.x;
    int b = blockIdx.x;
    int lo = b * CAP;
    int hi = lo + bcursor[b];
    sh[tid] = 0;
    __syncthreads();
    for (int i = lo + tid; i < hi; i += 256) atomicAdd(&sh[(bsorted[i] >> 16) & 255], 1);
    __syncthreads();
    int v = sh[tid];
    __syncthreads();
    sh[tid] = v;
    __syncthreads();
    for (int off = 1; off < 256; off <<= 1) {
        int t = (tid >= off) ? sh[tid - off] : 0;
        __syncthreads();
        sh[tid] += t;
        __syncthreads();
    }
    int excl = sh[tid] - v;
    int d = (b << 8) + tid;
    if (d < N) {
        rbe[d] = make_int2(lo + excl, lo + excl + v);
        dinv[d] = 1.0f / (float)(v > 1 ? v : 1);
    }
    cur[tid] = lo + excl;
    __syncthreads();
    for (int i = lo + tid; i < hi; i += 256) {
        unsigned pk = bsorted[i];
        int p = atomicAdd(&cur[(pk >> 16) & 255], 1);
        csr[p] = (int)(pk & 0xffffu) << 6;
    }
}

// ---------- MFMA dual GEMM, bf16 input: Ab = bf16(X@Ws+b), T8 halves = fp8(X@Wn) ----------
__global__ __launch_bounds__(256) void k_mfma_dual(
    const unsigned short* __restrict__ Xin,
    const unsigned short* __restrict__ WsT, const unsigned short* __restrict__ WnT,
    const float* __restrict__ bias, unsigned short* __restrict__ Ab,
    unsigned char* __restrict__ T8, int N) {
    __shared__ unsigned short xs[64][136];
    int tid = threadIdx.x;
    int br = blockIdx.x << 6;
    #pragma unroll
    for (int it = 0; it < 4; ++it) {
        int idx = tid + it * 256;
        int row = idx >> 4;
        int co = (idx & 15) << 3;
        int n = br + row;
        uint4 pk = make_uint4(0, 0, 0, 0);
        if (n < N) pk = *(const uint4*)(Xin + (size_t)n * 128 + co);
        *(uint4*)&xs[row][co] = pk;
    }
    __syncthreads();
    int wave = tid >> 6;
    int lane = tid & 63;
    int lrow = lane & 15;
    int kg = lane >> 4;
    int colbase = wave << 5;
    f32x4 acc[4][2][2];
    #pragma unroll
    for (int r = 0; r < 4; ++r)
        #pragma unroll
        for (int c = 0; c < 2; ++c) {
            acc[r][c][0] = (f32x4){0.f, 0.f, 0.f, 0.f};
            acc[r][c][1] = (f32x4){0.f, 0.f, 0.f, 0.f};
        }
    #pragma unroll
    for (int ks = 0; ks < 4; ++ks) {
        int kb = ks * 32 + kg * 8;
        bf16x8 af[4];
        #pragma unroll
        for (int r = 0; r < 4; ++r) af[r] = *(const bf16x8*)&xs[r * 16 + lrow][kb];
        bf16x8 bS[2], bN[2];
        #pragma unroll
        for (int c = 0; c < 2; ++c) {
            int col = colbase + c * 16 + lrow;
            bS[c] = *(const bf16x8*)(WsT + (size_t)col * 128 + kb);
            bN[c] = *(const bf16x8*)(WnT + (size_t)col * 128 + kb);
        }
        #pragma unroll
        for (int r = 0; r < 4; ++r)
            #pragma unroll
            for (int c = 0; c < 2; ++c) {
                acc[r][c][0] = __builtin_amdgcn_mfma_f32_16x16x32_bf16(af[r], bS[c], acc[r][c][0], 0, 0, 0);
                acc[r][c][1] = __builtin_amdgcn_mfma_f32_16x16x32_bf16(af[r], bN[c], acc[r][c][1], 0, 0, 0);
            }
    }
    #pragma unroll
    for (int r = 0; r < 4; ++r)
        #pragma unroll
        for (int c = 0; c < 2; ++c) {
            int col = colbase + c * 16 + lrow;
            float bv = bias[col];
            int hh = col >> 6, cl = col & 63;
            #pragma unroll
            for (int q = 0; q < 4; ++q) {
                int n = br + r * 16 + kg * 4 + q;
                if (n < N) {
                    Ab[(size_t)n * 128 + col] = f2bf(acc[r][c][0][q] + bv);
                    T8[((size_t)hh * N + n) * 64 + cl] = f2fp8(acc[r][c][1][q]);
                }
            }
        }
}

// ---------- agg layers 0/1: wave = (node, col-half); 64B half-rows, byte/lane ----------
__global__ __launch_bounds__(256) void k_agg_relu(
    const unsigned char* __restrict__ T8, const unsigned short* __restrict__ Ab,
    const float* __restrict__ dinv, const int2* __restrict__ rbe,
    const int* __restrict__ csr, unsigned short* __restrict__ Hb, int N) {
    int gw = (blockIdx.x * 256 + threadIdx.x) >> 6;
    if (gw >= 2 * N) return;
    int h = (gw >= N) ? 1 : 0;
    int w = gw - h * N;
    int lane = threadIdx.x & 63;
    const unsigned char* Tp = T8 + (size_t)h * N * 64;
    int2 be = rbe[w];
    int e = be.x, ee = be.y;
    float a = 0.f;
    for (; e + 8 <= ee; e += 8) {
        int o[8];
        #pragma unroll
        for (int j = 0; j < 8; ++j) o[j] = csr[e + j];
        unsigned char v[8];
        #pragma unroll
        for (int j = 0; j < 8; ++j) v[j] = Tp[(size_t)o[j] + lane];
        #pragma unroll
        for (int j = 0; j < 8; ++j) {
            f32x2 d = __builtin_amdgcn_cvt_pk_f32_fp8((unsigned)v[j], false);
            a += d.x;
        }
    }
    for (; e < ee; ++e) {
        f32x2 d = __builtin_amdgcn_cvt_pk_f32_fp8((unsigned)Tp[(size_t)csr[e] + lane], false);
        a += d.x;
    }
    int col = (h << 6) + lane;
    float di = dinv[w];
    float aself = bf2f((unsigned)Ab[(size_t)w * 128 + col]);
    float o = fmaxf(aself + a * di, 0.f);
    Hb[(size_t)w * 128 + col] = f2bf(o);
}

// ---------- layer-2 MFMA: self sums -> Sb (bf16 pairs), neighbor pairs -> T8 halves ----------
// T8 (layer 2): [2 halves][N][32] ushort pairs (byte0 = h-path, byte1 = z-path), 64B half-rows
__global__ __launch_bounds__(256) void k_mfma_layer2(
    const unsigned short* __restrict__ Hb, const float* __restrict__ NZ,
    const unsigned short* __restrict__ WTcat, const float* __restrict__ b2,
    unsigned short* __restrict__ Sb, unsigned short* __restrict__ T8p, int N) {
    __shared__ unsigned short xh[64][136];
    __shared__ unsigned short xz[64][136];
    int tid = threadIdx.x;
    int br = blockIdx.x << 6;
    #pragma unroll
    for (int it = 0; it < 4; ++it) {
        int idx = tid + it * 256;
        int row = idx >> 4;
        int co = (idx & 15) << 3;
        int n = br + row;
        uint4 ph = make_uint4(0, 0, 0, 0), pz = make_uint4(0, 0, 0, 0);
        if (n < N) {
            ph = *(const uint4*)(Hb + (size_t)n * 128 + co);
            float4 v0 = *(const float4*)(NZ + (size_t)n * 128 + co);
            float4 v1 = *(const float4*)(NZ + (size_t)n * 128 + co + 4);
            pz.x = (unsigned)f2bf(v0.x) | ((unsigned)f2bf(v0.y) << 16);
            pz.y = (unsigned)f2bf(v0.z) | ((unsigned)f2bf(v0.w) << 16);
            pz.z = (unsigned)f2bf(v1.x) | ((unsigned)f2bf(v1.y) << 16);
            pz.w = (unsigned)f2bf(v1.z) | ((unsigned)f2bf(v1.w) << 16);
        }
        *(uint4*)&xh[row][co] = ph;
        *(uint4*)&xz[row][co] = pz;
    }
    __syncthreads();
    int wave = tid >> 6;
    int lane = tid & 63;
    int lrow = lane & 15;
    int kg = lane >> 4;
    int colbase = wave << 5;
    f32x4 acc[4][2][2];
    #pragma unroll
    for (int r = 0; r < 4; ++r)
        #pragma unroll
        for (int c = 0; c < 2; ++c) {
            acc[r][c][0] = (f32x4){0.f, 0.f, 0.f, 0.f};
            acc[r][c][1] = (f32x4){0.f, 0.f, 0.f, 0.f};
        }
    #pragma unroll
    for (int ks = 0; ks < 4; ++ks) {
        int kb = ks * 32 + kg * 8;
        bf16x8 ah[4], az[4];
        #pragma unroll
        for (int r = 0; r < 4; ++r) {
            ah[r] = *(const bf16x8*)&xh[r * 16 + lrow][kb];
            az[r] = *(const bf16x8*)&xz[r * 16 + lrow][kb];
        }
        bf16x8 bw[2];
        #pragma unroll
        for (int c = 0; c < 2; ++c) {
            int col = colbase + c * 16 + lrow;
            bw[c] = *(const bf16x8*)(WTcat + (size_t)col * 128 + kb);
        }
        #pragma unroll
        for (int r = 0; r < 4; ++r)
            #pragma unroll
            for (int c = 0; c < 2; ++c) {
                acc[r][c][0] = __builtin_amdgcn_mfma_f32_16x16x32_bf16(ah[r], bw[c], acc[r][c][0], 0, 0, 0);
                acc[r][c][1] = __builtin_amdgcn_mfma_f32_16x16x32_bf16(az[r], bw[c], acc[r][c][1], 0, 0, 0);
            }
    }
    if (wave < 2) {
        #pragma unroll
        for (int r = 0; r < 4; ++r)
            #pragma unroll
            for (int c = 0; c < 2; ++c) {
                int j = colbase + c * 16 + lrow;
                float bv = b2[j];
                #pragma unroll
                for (int q = 0; q < 4; ++q) {
                    int n = br + r * 16 + kg * 4 + q;
                    if (n < N) {
                        float hs = acc[r][c][0][q] + bv;
                        float zs = acc[r][c][1][q];
                        unsigned pk = (unsigned)f2bf(hs) | ((unsigned)f2bf(hs + zs) << 16);
                        ((unsigned*)Sb)[(size_t)n * 64 + j] = pk;
                    }
                }
            }
    } else {
        #pragma unroll
        for (int r = 0; r < 4; ++r)
            #pragma unroll
            for (int c = 0; c < 2; ++c) {
                int j = colbase - 64 + c * 16 + lrow;   // 0..63 pair index
                int hh = j >> 5, jj = j & 31;
                #pragma unroll
                for (int q = 0; q < 4; ++q) {
                    int n = br + r * 16 + kg * 4 + q;
                    if (n < N) {
                        unsigned pk = __builtin_amdgcn_cvt_pk_fp8_f32(
                            acc[r][c][0][q], acc[r][c][1][q], 0, false);
                        T8p[((size_t)hh * N + n) * 32 + jj] = (unsigned short)(pk & 0xffffu);
                    }
                }
            }
    }
}

// ---------- layer-2 aggregation: wave = (node, pair-half); byte/lane, shfl to pair up ----------
__global__ __launch_bounds__(256) void k_agg_final2(
    const unsigned char* __restrict__ T8b, const unsigned short* __restrict__ Sb,
    const float* __restrict__ dinv, const int2* __restrict__ rbe,
    const int* __restrict__ csr, float* __restrict__ out, int N) {
    int gw = (blockIdx.x * 256 + threadIdx.x) >> 6;
    if (gw >= 2 * N) return;
    int h = (gw >= N) ? 1 : 0;
    int w = gw - h * N;
    int lane = threadIdx.x & 63;
    const unsigned char* Tp = T8b + (size_t)h * N * 64;
    int2 be = rbe[w];
    int e = be.x, ee = be.y;
    float s = 0.f;
    for (; e + 8 <= ee; e += 8) {
        int o[8];
        #pragma unroll
        for (int j = 0; j < 8; ++j) o[j] = csr[e + j];
        unsigned char v[8];
        #pragma unroll
        for (int j = 0; j < 8; ++j) v[j] = Tp[(size_t)o[j] + lane];
        #pragma unroll
        for (int j = 0; j < 8; ++j) {
            f32x2 d = __builtin_amdgcn_cvt_pk_f32_fp8((unsigned)v[j], false);
            s += d.x;
        }
    }
    for (; e < ee; ++e) {
        f32x2 d = __builtin_amdgcn_cvt_pk_f32_fp8((unsigned)Tp[(size_t)csr[e] + lane], false);
        s += d.x;
    }
    float partner = __shfl_xor(s, 1, 64);
    int col = (h << 5) + (lane >> 1);      // 0..63
    float di = dinv[w];
    unsigned sv = ((const unsigned*)Sb)[(size_t)w * 64 + col];
    float* orow = out + (size_t)w * 128;
    if ((lane & 1) == 0) {
        orow[64 + col] = bf2f(sv & 0xffff) + s * di;            // h2: self + aggH/deg
    } else {
        orow[col] = bf2f(sv >> 16) + (partner + s) * di;        // hn2: self + (aggH+aggZ)/deg
    }
}

extern "C" void kernel_launch(void* const* d_in, const int* in_sizes, int n_in,
                              void* d_out, int out_size, void* d_ws, size_t ws_size,
                              hipStream_t stream) {
    const float* features = (const float*)d_in[0];
    const float* noise    = (const float*)d_in[1];
    const float* Ws0 = (const float*)d_in[2];
    const float* Wn0 = (const float*)d_in[3];
    const float* b0  = (const float*)d_in[4];
    const float* Ws1 = (const float*)d_in[5];
    const float* Wn1 = (const float*)d_in[6];
    const float* b1  = (const float*)d_in[7];
    const float* Ws2 = (const float*)d_in[8];
    const float* Wn2 = (const float*)d_in[9];
    const float* b2  = (const float*)d_in[10];
    const int* esrc = (const int*)d_in[11];
    const int* edst = (const int*)d_in[12];
    int N = in_sizes[0] / 128;
    int E = in_sizes[11];
    float* out = (float*)d_out;

    // workspace
    unsigned short* Ab = (unsigned short*)d_ws;            // [N][128] bf16
    unsigned short* Hb = Ab + (size_t)N * 128;             // [N][128] bf16
    unsigned short* Sb = Hb + (size_t)N * 128;             // [N][64] bf16 pairs
    unsigned char*  T8 = (unsigned char*)(Sb + (size_t)N * 128); // [2][N][64] fp8 (N*128 B)
    unsigned short* WT0s = (unsigned short*)(T8 + (size_t)N * 128);
    unsigned short* WT0n = WT0s + 128 * 128;
    unsigned short* WT1s = WT0n + 128 * 128;
    unsigned short* WT1n = WT1s + 128 * 128;
    unsigned short* WT2  = WT1n + 128 * 128;
    float* dinv = (float*)(WT2 + 128 * 128);               // [N]
    int2* rbe  = (int2*)(dinv + N);                        // [N]
    int* csr   = (int*)(rbe + N);                          // [256*CAP]
    unsigned* bsorted = (unsigned*)(csr + 256 * CAP);      // [256*CAP]
    int* bcursor = (int*)(bsorted + 256 * CAP);            // [256]

    int nbk = (N + 255) >> 8;
    int ech = (E + CHUNK - 1) / CHUNK;
    int g64 = (N + 63) / 64;

    k_wt<<<320, 256, 0, stream>>>(Ws0, Wn0, Ws1, Wn1, Ws2, Wn2,
                                  WT0s, WT0n, WT1s, WT1n, WT2, bcursor);
    k_scatter_gemm0<<<ech + g64, 256, 0, stream>>>(esrc, edst, bcursor, bsorted, E, ech,
                                                   features, WT0s, WT0n, b0, Ab, T8, N);
    k_bucket_csr<<<nbk, 256, 0, stream>>>(bsorted, bcursor, rbe, dinv, csr, N);

    int ablocks = ((size_t)2 * N * 64 + 255) / 256;   // wave = (node, half)

    k_agg_relu<<<ablocks, 256, 0, stream>>>(T8, Ab, dinv, rbe, csr, Hb, N);
    k_mfma_dual<<<g64, 256, 0, stream>>>(Hb, WT1s, WT1n, b1, Ab, T8, N);
    k_agg_relu<<<ablocks, 256, 0, stream>>>(T8, Ab, dinv, rbe, csr, Hb, N);
    k_mfma_layer2<<<g64, 256, 0, stream>>>(Hb, noise, WT2, b2, Sb, (unsigned short*)T8, N);
    k_agg_final2<<<ablocks, 256, 0, stream>>>(T8, Sb, dinv, rbe, csr, out, N);
}

// Round 15
// 180.774 us; speedup vs baseline: 1.5258x; 1.5258x over previous
//
#include <hip/hip_runtime.h>

typedef __attribute__((ext_vector_type(8))) short bf16x8;
typedef __attribute__((ext_vector_type(4))) float f32x4;
typedef __attribute__((ext_vector_type(2))) float f32x2;

__device__ __forceinline__ unsigned short f2bf(float x) {
    union { float f; unsigned u; } v; v.f = x;
    unsigned r = v.u + 0x7FFFu + ((v.u >> 16) & 1u);
    return (unsigned short)(r >> 16);
}
__device__ __forceinline__ float bf2f(unsigned u) {
    union { unsigned u; float f; } v; v.u = u << 16;
    return v.f;
}
__device__ __forceinline__ unsigned char f2fp8(float x) {
    return (unsigned char)(__builtin_amdgcn_cvt_pk_fp8_f32(x, x, 0, false) & 0xff);
}

#define CHUNK 4096
#define CAP 4608

// ---------- K1: weight transpose + zero bcursor ----------
__global__ __launch_bounds__(256) void k_wt(
    const float* __restrict__ Ws0, const float* __restrict__ Wn0,
    const float* __restrict__ Ws1, const float* __restrict__ Wn1,
    const float* __restrict__ Ws2, const float* __restrict__ Wn2,
    unsigned short* __restrict__ WT0s, unsigned short* __restrict__ WT0n,
    unsigned short* __restrict__ WT1s, unsigned short* __restrict__ WT1n,
    unsigned short* __restrict__ WT2, int* __restrict__ bcursor) {
    int tid = threadIdx.x;
    if (blockIdx.x == 0) bcursor[tid] = 0;
    int i = blockIdx.x * 256 + tid;
    if (i < 16384)      { int j = i;         WT0s[j] = f2bf(Ws0[(j & 127) * 128 + (j >> 7)]); }
    else if (i < 32768) { int j = i - 16384; WT0n[j] = f2bf(Wn0[(j & 127) * 128 + (j >> 7)]); }
    else if (i < 49152) { int j = i - 32768; WT1s[j] = f2bf(Ws1[(j & 127) * 128 + (j >> 7)]); }
    else if (i < 65536) { int j = i - 49152; WT1n[j] = f2bf(Wn1[(j & 127) * 128 + (j >> 7)]); }
    else if (i < 73728) { int j = i - 65536; WT2[j] = f2bf(Ws2[(j & 127) * 64 + (j >> 7)]); }
    else if (i < 81920) { int j = i - 73728; WT2[8192 + j] = f2bf(Wn2[(j & 127) * 64 + (j >> 7)]); }
}

// ---------- K2: bucket scatter (blocks < ech) UNION layer-0 GEMM ----------
__global__ __launch_bounds__(256) void k_scatter_gemm0(
    const int* __restrict__ esrc, const int* __restrict__ edst,
    int* __restrict__ bcursor, unsigned* __restrict__ bsorted, int E, int ech,
    const float* __restrict__ Xf,
    const unsigned short* __restrict__ WsT, const unsigned short* __restrict__ WnT,
    const float* __restrict__ bias, unsigned short* __restrict__ Ab,
    unsigned char* __restrict__ T8, int N) {
    __shared__ uint4 smem[1216];
    int tid = threadIdx.x;
    if ((int)blockIdx.x < ech) {
        unsigned* stage = (unsigned*)smem;
        int* hist = (int*)(stage + CHUNK);
        int* base = hist + 256;
        int* cur  = base + 256;
        hist[tid] = 0;
        __syncthreads();
        int e0 = blockIdx.x * CHUNK;
        int cnt = min(CHUNK, E - e0);
        for (int i = tid; i < cnt; i += 256) {
            int d = edst[e0 + i], s = esrc[e0 + i];
            stage[i] = ((unsigned)d << 16) | (unsigned)s;
            atomicAdd(&hist[d >> 8], 1);
        }
        __syncthreads();
        int h = hist[tid];
        base[tid] = h ? (tid * CAP + atomicAdd(&bcursor[tid], h)) : 0;
        cur[tid] = 0;
        __syncthreads();
        for (int i = tid; i < cnt; i += 256) {
            unsigned pk = stage[i];
            int b = pk >> 24;
            int p = base[b] + atomicAdd(&cur[b], 1);
            bsorted[p] = pk;
        }
    } else {
        unsigned short (*xs)[136] = (unsigned short(*)[136])smem;
        int br = (blockIdx.x - ech) << 6;
        #pragma unroll
        for (int it = 0; it < 4; ++it) {
            int idx = tid + it * 256;
            int row = idx >> 4;
            int co = (idx & 15) << 3;
            int n = br + row;
            uint4 pk = make_uint4(0, 0, 0, 0);
            if (n < N) {
                float4 v0 = *(const float4*)(Xf + (size_t)n * 128 + co);
                float4 v1 = *(const float4*)(Xf + (size_t)n * 128 + co + 4);
                pk.x = (unsigned)f2bf(v0.x) | ((unsigned)f2bf(v0.y) << 16);
                pk.y = (unsigned)f2bf(v0.z) | ((unsigned)f2bf(v0.w) << 16);
                pk.z = (unsigned)f2bf(v1.x) | ((unsigned)f2bf(v1.y) << 16);
                pk.w = (unsigned)f2bf(v1.z) | ((unsigned)f2bf(v1.w) << 16);
            }
            *(uint4*)&xs[row][co] = pk;
        }
        __syncthreads();
        int wave = tid >> 6;
        int lane = tid & 63;
        int lrow = lane & 15;
        int kg = lane >> 4;
        int colbase = wave << 5;
        f32x4 acc[4][2][2];
        #pragma unroll
        for (int r = 0; r < 4; ++r)
            #pragma unroll
            for (int c = 0; c < 2; ++c) {
                acc[r][c][0] = (f32x4){0.f, 0.f, 0.f, 0.f};
                acc[r][c][1] = (f32x4){0.f, 0.f, 0.f, 0.f};
            }
        #pragma unroll
        for (int ks = 0; ks < 4; ++ks) {
            int kb = ks * 32 + kg * 8;
            bf16x8 af[4];
            #pragma unroll
            for (int r = 0; r < 4; ++r) af[r] = *(const bf16x8*)&xs[r * 16 + lrow][kb];
            bf16x8 bS[2], bN[2];
            #pragma unroll
            for (int c = 0; c < 2; ++c) {
                int col = colbase + c * 16 + lrow;
                bS[c] = *(const bf16x8*)(WsT + (size_t)col * 128 + kb);
                bN[c] = *(const bf16x8*)(WnT + (size_t)col * 128 + kb);
            }
            #pragma unroll
            for (int r = 0; r < 4; ++r)
                #pragma unroll
                for (int c = 0; c < 2; ++c) {
                    acc[r][c][0] = __builtin_amdgcn_mfma_f32_16x16x32_bf16(af[r], bS[c], acc[r][c][0], 0, 0, 0);
                    acc[r][c][1] = __builtin_amdgcn_mfma_f32_16x16x32_bf16(af[r], bN[c], acc[r][c][1], 0, 0, 0);
                }
        }
        #pragma unroll
        for (int r = 0; r < 4; ++r)
            #pragma unroll
            for (int c = 0; c < 2; ++c) {
                int col = colbase + c * 16 + lrow;
                float bv = bias[col];
                #pragma unroll
                for (int q = 0; q < 4; ++q) {
                    int n = br + r * 16 + kg * 4 + q;
                    if (n < N) {
                        Ab[(size_t)n * 128 + col] = f2bf(acc[r][c][0][q] + bv);
                        T8[(size_t)n * 128 + col] = f2fp8(acc[r][c][1][q]);
                    }
                }
            }
    }
}

// ---------- K3: per-bucket CSR finalize; csr = pre-scaled offsets (src<<6) ----------
__global__ __launch_bounds__(256) void k_bucket_csr(const unsigned* __restrict__ bsorted,
                                                    const int* __restrict__ bcursor,
                                                    int2* __restrict__ rbe,
                                                    float* __restrict__ dinv,
                                                    int* __restrict__ csr, int N) {
    __shared__ int sh[256];
    __shared__ int cur[256];
    int tid = threadIdx.x;
    int b = blockIdx.x;
    int lo = b * CAP;
    int hi = lo + bcursor[b];
    sh[tid] = 0;
    __syncthreads();
    for (int i = lo + tid; i < hi; i += 256) atomicAdd(&sh[(bsorted[i] >> 16) & 255], 1);
    __syncthreads();
    int v = sh[tid];
    __syncthreads();
    sh[tid] = v;
    __syncthreads();
    for (int off = 1; off < 256; off <<= 1) {
        int t = (tid >= off) ? sh[tid - off] : 0;
        __syncthreads();
        sh[tid] += t;
        __syncthreads();
    }
    int excl = sh[tid] - v;
    int d = (b << 8) + tid;
    if (d < N) {
        rbe[d] = make_int2(lo + excl, lo + excl + v);
        dinv[d] = 1.0f / (float)(v > 1 ? v : 1);
    }
    cur[tid] = lo + excl;
    __syncthreads();
    for (int i = lo + tid; i < hi; i += 256) {
        unsigned pk = bsorted[i];
        int p = atomicAdd(&cur[(pk >> 16) & 255], 1);
        csr[p] = (int)(pk & 0xffffu) << 6;
    }
}

// ---------- MFMA dual GEMM, bf16 input: Ab = bf16(X@Ws+b), T8 = fp8(X@Wn) ----------
__global__ __launch_bounds__(256) void k_mfma_dual(
    const unsigned short* __restrict__ Xin,
    const unsigned short* __restrict__ WsT, const unsigned short* __restrict__ WnT,
    const float* __restrict__ bias, unsigned short* __restrict__ Ab,
    unsigned char* __restrict__ T8, int N) {
    __shared__ unsigned short xs[64][136];
    int tid = threadIdx.x;
    int br = blockIdx.x << 6;
    #pragma unroll
    for (int it = 0; it < 4; ++it) {
        int idx = tid + it * 256;
        int row = idx >> 4;
        int co = (idx & 15) << 3;
        int n = br + row;
        uint4 pk = make_uint4(0, 0, 0, 0);
        if (n < N) pk = *(const uint4*)(Xin + (size_t)n * 128 + co);
        *(uint4*)&xs[row][co] = pk;
    }
    __syncthreads();
    int wave = tid >> 6;
    int lane = tid & 63;
    int lrow = lane & 15;
    int kg = lane >> 4;
    int colbase = wave << 5;
    f32x4 acc[4][2][2];
    #pragma unroll
    for (int r = 0; r < 4; ++r)
        #pragma unroll
        for (int c = 0; c < 2; ++c) {
            acc[r][c][0] = (f32x4){0.f, 0.f, 0.f, 0.f};
            acc[r][c][1] = (f32x4){0.f, 0.f, 0.f, 0.f};
        }
    #pragma unroll
    for (int ks = 0; ks < 4; ++ks) {
        int kb = ks * 32 + kg * 8;
        bf16x8 af[4];
        #pragma unroll
        for (int r = 0; r < 4; ++r) af[r] = *(const bf16x8*)&xs[r * 16 + lrow][kb];
        bf16x8 bS[2], bN[2];
        #pragma unroll
        for (int c = 0; c < 2; ++c) {
            int col = colbase + c * 16 + lrow;
            bS[c] = *(const bf16x8*)(WsT + (size_t)col * 128 + kb);
            bN[c] = *(const bf16x8*)(WnT + (size_t)col * 128 + kb);
        }
        #pragma unroll
        for (int r = 0; r < 4; ++r)
            #pragma unroll
            for (int c = 0; c < 2; ++c) {
                acc[r][c][0] = __builtin_amdgcn_mfma_f32_16x16x32_bf16(af[r], bS[c], acc[r][c][0], 0, 0, 0);
                acc[r][c][1] = __builtin_amdgcn_mfma_f32_16x16x32_bf16(af[r], bN[c], acc[r][c][1], 0, 0, 0);
            }
    }
    #pragma unroll
    for (int r = 0; r < 4; ++r)
        #pragma unroll
        for (int c = 0; c < 2; ++c) {
            int col = colbase + c * 16 + lrow;
            float bv = bias[col];
            #pragma unroll
            for (int q = 0; q < 4; ++q) {
                int n = br + r * 16 + kg * 4 + q;
                if (n < N) {
                    Ab[(size_t)n * 128 + col] = f2bf(acc[r][c][0][q] + bv);
                    T8[(size_t)n * 128 + col] = f2fp8(acc[r][c][1][q]);
                }
            }
        }
}

// ---------- agg layers 0/1: Hb = bf16(relu(Ab + agg(T8)*dinv)); fp8 rows, batch-16 ----------
__global__ __launch_bounds__(256) void k_agg_relu(
    const unsigned short* __restrict__ T8p, const unsigned* __restrict__ Av,
    const float* __restrict__ dinv, const int2* __restrict__ rbe,
    const int* __restrict__ csr, unsigned* __restrict__ Hv, int N) {
    int w = (blockIdx.x * 256 + threadIdx.x) >> 6;
    int lane = threadIdx.x & 63;
    if (w >= N) return;
    int2 be = rbe[w];
    int e = be.x, ee = be.y;
    float ax = 0.f, ay = 0.f;
    for (; e + 16 <= ee; e += 16) {
        int o[16];
        #pragma unroll
        for (int j = 0; j < 16; ++j) o[j] = csr[e + j];
        unsigned short v[16];
        #pragma unroll
        for (int j = 0; j < 16; ++j) v[j] = T8p[(size_t)o[j] + lane];
        #pragma unroll
        for (int j = 0; j < 16; ++j) {
            f32x2 d = __builtin_amdgcn_cvt_pk_f32_fp8((unsigned)v[j], false);
            ax += d.x; ay += d.y;
        }
    }
    for (; e + 4 <= ee; e += 4) {
        int o[4];
        #pragma unroll
        for (int j = 0; j < 4; ++j) o[j] = csr[e + j];
        unsigned short v[4];
        #pragma unroll
        for (int j = 0; j < 4; ++j) v[j] = T8p[(size_t)o[j] + lane];
        #pragma unroll
        for (int j = 0; j < 4; ++j) {
            f32x2 d = __builtin_amdgcn_cvt_pk_f32_fp8((unsigned)v[j], false);
            ax += d.x; ay += d.y;
        }
    }
    for (; e < ee; ++e) {
        f32x2 d = __builtin_amdgcn_cvt_pk_f32_fp8((unsigned)T8p[(size_t)csr[e] + lane], false);
        ax += d.x; ay += d.y;
    }
    float di = dinv[w];
    unsigned av = Av[(size_t)w * 64 + lane];
    float ox = fmaxf(bf2f(av & 0xffff) + ax * di, 0.f);
    float oy = fmaxf(bf2f(av >> 16) + ay * di, 0.f);
    Hv[(size_t)w * 64 + lane] = (unsigned)f2bf(ox) | ((unsigned)f2bf(oy) << 16);
}

// ---------- layer-2 MFMA: self sums -> Sb (bf16 pairs), neighbor pairs -> T8 (fp8 pairs) ----------
__global__ __launch_bounds__(256) void k_mfma_layer2(
    const unsigned short* __restrict__ Hb, const float* __restrict__ NZ,
    const unsigned short* __restrict__ WTcat, const float* __restrict__ b2,
    unsigned short* __restrict__ Sb, unsigned short* __restrict__ T8p, int N) {
    __shared__ unsigned short xh[64][136];
    __shared__ unsigned short xz[64][136];
    int tid = threadIdx.x;
    int br = blockIdx.x << 6;
    #pragma unroll
    for (int it = 0; it < 4; ++it) {
        int idx = tid + it * 256;
        int row = idx >> 4;
        int co = (idx & 15) << 3;
        int n = br + row;
        uint4 ph = make_uint4(0, 0, 0, 0), pz = make_uint4(0, 0, 0, 0);
        if (n < N) {
            ph = *(const uint4*)(Hb + (size_t)n * 128 + co);
            float4 v0 = *(const float4*)(NZ + (size_t)n * 128 + co);
            float4 v1 = *(const float4*)(NZ + (size_t)n * 128 + co + 4);
            pz.x = (unsigned)f2bf(v0.x) | ((unsigned)f2bf(v0.y) << 16);
            pz.y = (unsigned)f2bf(v0.z) | ((unsigned)f2bf(v0.w) << 16);
            pz.z = (unsigned)f2bf(v1.x) | ((unsigned)f2bf(v1.y) << 16);
            pz.w = (unsigned)f2bf(v1.z) | ((unsigned)f2bf(v1.w) << 16);
        }
        *(uint4*)&xh[row][co] = ph;
        *(uint4*)&xz[row][co] = pz;
    }
    __syncthreads();
    int wave = tid >> 6;
    int lane = tid & 63;
    int lrow = lane & 15;
    int kg = lane >> 4;
    int colbase = wave << 5;
    f32x4 acc[4][2][2];
    #pragma unroll
    for (int r = 0; r < 4; ++r)
        #pragma unroll
        for (int c = 0; c < 2; ++c) {
            acc[r][c][0] = (f32x4){0.f, 0.f, 0.f, 0.f};
            acc[r][c][1] = (f32x4){0.f, 0.f, 0.f, 0.f};
        }
    #pragma unroll
    for (int ks = 0; ks < 4; ++ks) {
        int kb = ks * 32 + kg * 8;
        bf16x8 ah[4], az[4];
        #pragma unroll
        for (int r = 0; r < 4; ++r) {
            ah[r] = *(const bf16x8*)&xh[r * 16 + lrow][kb];
            az[r] = *(const bf16x8*)&xz[r * 16 + lrow][kb];
        }
        bf16x8 bw[2];
        #pragma unroll
        for (int c = 0; c < 2; ++c) {
            int col = colbase + c * 16 + lrow;
            bw[c] = *(const bf16x8*)(WTcat + (size_t)col * 128 + kb);
        }
        #pragma unroll
        for (int r = 0; r < 4; ++r)
            #pragma unroll
            for (int c = 0; c < 2; ++c) {
                acc[r][c][0] = __builtin_amdgcn_mfma_f32_16x16x32_bf16(ah[r], bw[c], acc[r][c][0], 0, 0, 0);
                acc[r][c][1] = __builtin_amdgcn_mfma_f32_16x16x32_bf16(az[r], bw[c], acc[r][c][1], 0, 0, 0);
            }
    }
    if (wave < 2) {
        #pragma unroll
        for (int r = 0; r < 4; ++r)
            #pragma unroll
            for (int c = 0; c < 2; ++c) {
                int j = colbase + c * 16 + lrow;
                float bv = b2[j];
                #pragma unroll
                for (int q = 0; q < 4; ++q) {
                    int n = br + r * 16 + kg * 4 + q;
                    if (n < N) {
                        float hs = acc[r][c][0][q] + bv;
                        float zs = acc[r][c][1][q];
                        unsigned pk = (unsigned)f2bf(hs) | ((unsigned)f2bf(hs + zs) << 16);
                        ((unsigned*)Sb)[(size_t)n * 64 + j] = pk;
                    }
                }
            }
    } else {
        #pragma unroll
        for (int r = 0; r < 4; ++r)
            #pragma unroll
            for (int c = 0; c < 2; ++c) {
                int j = colbase - 64 + c * 16 + lrow;
                #pragma unroll
                for (int q = 0; q < 4; ++q) {
                    int n = br + r * 16 + kg * 4 + q;
                    if (n < N) {
                        unsigned pk = __builtin_amdgcn_cvt_pk_fp8_f32(
                            acc[r][c][0][q], acc[r][c][1][q], 0, false);
                        T8p[(size_t)n * 64 + j] = (unsigned short)(pk & 0xffffu);
                    }
                }
            }
    }
}

// ---------- layer-2 aggregation: out = self + agg(fp8 pairs), batch-16 ----------
__global__ __launch_bounds__(256) void k_agg_final2(
    const unsigned short* __restrict__ T8p, const unsigned short* __restrict__ Sb,
    const float* __restrict__ dinv, const int2* __restrict__ rbe,
    const int* __restrict__ csr, float* __restrict__ out, int N) {
    int w = (blockIdx.x * 256 + threadIdx.x) >> 6;
    int lane = threadIdx.x & 63;
    if (w >= N) return;
    int2 be = rbe[w];
    int e = be.x, ee = be.y;
    float ax = 0.f, ay = 0.f;
    for (; e + 16 <= ee; e += 16) {
        int o[16];
        #pragma unroll
        for (int j = 0; j < 16; ++j) o[j] = csr[e + j];
        unsigned short v[16];
        #pragma unroll
        for (int j = 0; j < 16; ++j) v[j] = T8p[(size_t)o[j] + lane];
        #pragma unroll
        for (int j = 0; j < 16; ++j) {
            f32x2 d = __builtin_amdgcn_cvt_pk_f32_fp8((unsigned)v[j], false);
            ax += d.x; ay += d.y;
        }
    }
    for (; e + 4 <= ee; e += 4) {
        int o[4];
        #pragma unroll
        for (int j = 0; j < 4; ++j) o[j] = csr[e + j];
        unsigned short v[4];
        #pragma unroll
        for (int j = 0; j < 4; ++j) v[j] = T8p[(size_t)o[j] + lane];
        #pragma unroll
        for (int j = 0; j < 4; ++j) {
            f32x2 d = __builtin_amdgcn_cvt_pk_f32_fp8((unsigned)v[j], false);
            ax += d.x; ay += d.y;
        }
    }
    for (; e < ee; ++e) {
        f32x2 d = __builtin_amdgcn_cvt_pk_f32_fp8((unsigned)T8p[(size_t)csr[e] + lane], false);
        ax += d.x; ay += d.y;
    }
    float di = dinv[w];
    unsigned sv = ((const unsigned*)Sb)[(size_t)w * 64 + lane];
    float* orow = out + (size_t)w * 128;
    orow[64 + lane] = bf2f(sv & 0xffff) + ax * di;
    orow[lane]      = bf2f(sv >> 16) + (ax + ay) * di;
}

extern "C" void kernel_launch(void* const* d_in, const int* in_sizes, int n_in,
                              void* d_out, int out_size, void* d_ws, size_t ws_size,
                              hipStream_t stream) {
    const float* features = (const float*)d_in[0];
    const float* noise    = (const float*)d_in[1];
    const float* Ws0 = (const float*)d_in[2];
    const float* Wn0 = (const float*)d_in[3];
    const float* b0  = (const float*)d_in[4];
    const float* Ws1 = (const float*)d_in[5];
    const float* Wn1 = (const float*)d_in[6];
    const float* b1  = (const float*)d_in[7];
    const float* Ws2 = (const float*)d_in[8];
    const float* Wn2 = (const float*)d_in[9];
    const float* b2  = (const float*)d_in[10];
    const int* esrc = (const int*)d_in[11];
    const int* edst = (const int*)d_in[12];
    int N = in_sizes[0] / 128;
    int E = in_sizes[11];
    float* out = (float*)d_out;

    // workspace
    unsigned short* Ab = (unsigned short*)d_ws;            // [N][128] bf16
    unsigned short* Hb = Ab + (size_t)N * 128;             // [N][128] bf16
    unsigned short* Sb = Hb + (size_t)N * 128;             // [N][64] bf16 pairs
    unsigned char*  T8 = (unsigned char*)(Sb + (size_t)N * 128); // [N][128] fp8 / [N][64] pairs
    unsigned short* WT0s = (unsigned short*)(T8 + (size_t)N * 128);
    unsigned short* WT0n = WT0s + 128 * 128;
    unsigned short* WT1s = WT0n + 128 * 128;
    unsigned short* WT1n = WT1s + 128 * 128;
    unsigned short* WT2  = WT1n + 128 * 128;
    float* dinv = (float*)(WT2 + 128 * 128);               // [N]
    int2* rbe  = (int2*)(dinv + N);                        // [N]
    int* csr   = (int*)(rbe + N);                          // [256*CAP]
    unsigned* bsorted = (unsigned*)(csr + 256 * CAP);      // [256*CAP]
    int* bcursor = (int*)(bsorted + 256 * CAP);            // [256]

    int nbk = (N + 255) >> 8;
    int ech = (E + CHUNK - 1) / CHUNK;
    int g64 = (N + 63) / 64;

    k_wt<<<320, 256, 0, stream>>>(Ws0, Wn0, Ws1, Wn1, Ws2, Wn2,
                                  WT0s, WT0n, WT1s, WT1n, WT2, bcursor);
    k_scatter_gemm0<<<ech + g64, 256, 0, stream>>>(esrc, edst, bcursor, bsorted, E, ech,
                                                   features, WT0s, WT0n, b0, Ab, T8, N);
    k_bucket_csr<<<nbk, 256, 0, stream>>>(bsorted, bcursor, rbe, dinv, csr, N);

    int ablocks = (N * 64 + 255) / 256;

    k_agg_relu<<<ablocks, 256, 0, stream>>>((const unsigned short*)T8, (const unsigned*)Ab,
                                            dinv, rbe, csr, (unsigned*)Hb, N);
    k_mfma_dual<<<g64, 256, 0, stream>>>(Hb, WT1s, WT1n, b1, Ab, T8, N);
    k_agg_relu<<<ablocks, 256, 0, stream>>>((const unsigned short*)T8, (const unsigned*)Ab,
                                            dinv, rbe, csr, (unsigned*)Hb, N);
    k_mfma_layer2<<<g64, 256, 0, stream>>>(Hb, noise, WT2, b2, Sb, (unsigned short*)T8, N);
    k_agg_final2<<<ablocks, 256, 0, stream>>>((const unsigned short*)T8, Sb, dinv, rbe, csr, out, N);
}

// Round 16
// 169.584 us; speedup vs baseline: 1.6265x; 1.0660x over previous
//
#include <hip/hip_runtime.h>

typedef __attribute__((ext_vector_type(8))) short bf16x8;
typedef __attribute__((ext_vector_type(4))) float f32x4;
typedef __attribute__((ext_vector_type(2))) float f32x2;

__device__ __forceinline__ unsigned short f2bf(float x) {
    union { float f; unsigned u; } v; v.f = x;
    unsigned r = v.u + 0x7FFFu + ((v.u >> 16) & 1u);
    return (unsigned short)(r >> 16);
}
__device__ __forceinline__ float bf2f(unsigned u) {
    union { unsigned u; float f; } v; v.u = u << 16;
    return v.f;
}
__device__ __forceinline__ unsigned char f2fp8(float x) {
    return (unsigned char)(__builtin_amdgcn_cvt_pk_fp8_f32(x, x, 0, false) & 0xff);
}

#define CHUNK 4096
#define CAP 4608

// ---------- K1: weight transpose + zero bcursor ----------
__global__ __launch_bounds__(256) void k_wt(
    const float* __restrict__ Ws0, const float* __restrict__ Wn0,
    const float* __restrict__ Ws1, const float* __restrict__ Wn1,
    const float* __restrict__ Ws2, const float* __restrict__ Wn2,
    unsigned short* __restrict__ WT0s, unsigned short* __restrict__ WT0n,
    unsigned short* __restrict__ WT1s, unsigned short* __restrict__ WT1n,
    unsigned short* __restrict__ WT2, int* __restrict__ bcursor) {
    int tid = threadIdx.x;
    if (blockIdx.x == 0) bcursor[tid] = 0;
    int i = blockIdx.x * 256 + tid;
    if (i < 16384)      { int j = i;         WT0s[j] = f2bf(Ws0[(j & 127) * 128 + (j >> 7)]); }
    else if (i < 32768) { int j = i - 16384; WT0n[j] = f2bf(Wn0[(j & 127) * 128 + (j >> 7)]); }
    else if (i < 49152) { int j = i - 32768; WT1s[j] = f2bf(Ws1[(j & 127) * 128 + (j >> 7)]); }
    else if (i < 65536) { int j = i - 49152; WT1n[j] = f2bf(Wn1[(j & 127) * 128 + (j >> 7)]); }
    else if (i < 73728) { int j = i - 65536; WT2[j] = f2bf(Ws2[(j & 127) * 64 + (j >> 7)]); }
    else if (i < 81920) { int j = i - 73728; WT2[8192 + j] = f2bf(Wn2[(j & 127) * 64 + (j >> 7)]); }
}

// ---------- K2: bucket scatter (blocks < ech) UNION layer-0 GEMM ----------
__global__ __launch_bounds__(256) void k_scatter_gemm0(
    const int* __restrict__ esrc, const int* __restrict__ edst,
    int* __restrict__ bcursor, unsigned* __restrict__ bsorted, int E, int ech,
    const float* __restrict__ Xf,
    const unsigned short* __restrict__ WsT, const unsigned short* __restrict__ WnT,
    const float* __restrict__ bias, unsigned short* __restrict__ Ab,
    unsigned char* __restrict__ T8, int N) {
    __shared__ uint4 smem[1216];
    int tid = threadIdx.x;
    if ((int)blockIdx.x < ech) {
        unsigned* stage = (unsigned*)smem;
        int* hist = (int*)(stage + CHUNK);
        int* base = hist + 256;
        int* cur  = base + 256;
        hist[tid] = 0;
        __syncthreads();
        int e0 = blockIdx.x * CHUNK;
        int cnt = min(CHUNK, E - e0);
        for (int i = tid; i < cnt; i += 256) {
            int d = edst[e0 + i], s = esrc[e0 + i];
            stage[i] = ((unsigned)d << 16) | (unsigned)s;
            atomicAdd(&hist[d >> 8], 1);
        }
        __syncthreads();
        int h = hist[tid];
        base[tid] = h ? (tid * CAP + atomicAdd(&bcursor[tid], h)) : 0;
        cur[tid] = 0;
        __syncthreads();
        for (int i = tid; i < cnt; i += 256) {
            unsigned pk = stage[i];
            int b = pk >> 24;
            int p = base[b] + atomicAdd(&cur[b], 1);
            bsorted[p] = pk;
        }
    } else {
        unsigned short (*xs)[136] = (unsigned short(*)[136])smem;
        int br = (blockIdx.x - ech) << 6;
        #pragma unroll
        for (int it = 0; it < 4; ++it) {
            int idx = tid + it * 256;
            int row = idx >> 4;
            int co = (idx & 15) << 3;
            int n = br + row;
            uint4 pk = make_uint4(0, 0, 0, 0);
            if (n < N) {
                float4 v0 = *(const float4*)(Xf + (size_t)n * 128 + co);
                float4 v1 = *(const float4*)(Xf + (size_t)n * 128 + co + 4);
                pk.x = (unsigned)f2bf(v0.x) | ((unsigned)f2bf(v0.y) << 16);
                pk.y = (unsigned)f2bf(v0.z) | ((unsigned)f2bf(v0.w) << 16);
                pk.z = (unsigned)f2bf(v1.x) | ((unsigned)f2bf(v1.y) << 16);
                pk.w = (unsigned)f2bf(v1.z) | ((unsigned)f2bf(v1.w) << 16);
            }
            *(uint4*)&xs[row][co] = pk;
        }
        __syncthreads();
        int wave = tid >> 6;
        int lane = tid & 63;
        int lrow = lane & 15;
        int kg = lane >> 4;
        int colbase = wave << 5;
        f32x4 acc[4][2][2];
        #pragma unroll
        for (int r = 0; r < 4; ++r)
            #pragma unroll
            for (int c = 0; c < 2; ++c) {
                acc[r][c][0] = (f32x4){0.f, 0.f, 0.f, 0.f};
                acc[r][c][1] = (f32x4){0.f, 0.f, 0.f, 0.f};
            }
        #pragma unroll
        for (int ks = 0; ks < 4; ++ks) {
            int kb = ks * 32 + kg * 8;
            bf16x8 af[4];
            #pragma unroll
            for (int r = 0; r < 4; ++r) af[r] = *(const bf16x8*)&xs[r * 16 + lrow][kb];
            bf16x8 bS[2], bN[2];
            #pragma unroll
            for (int c = 0; c < 2; ++c) {
                int col = colbase + c * 16 + lrow;
                bS[c] = *(const bf16x8*)(WsT + (size_t)col * 128 + kb);
                bN[c] = *(const bf16x8*)(WnT + (size_t)col * 128 + kb);
            }
            #pragma unroll
            for (int r = 0; r < 4; ++r)
                #pragma unroll
                for (int c = 0; c < 2; ++c) {
                    acc[r][c][0] = __builtin_amdgcn_mfma_f32_16x16x32_bf16(af[r], bS[c], acc[r][c][0], 0, 0, 0);
                    acc[r][c][1] = __builtin_amdgcn_mfma_f32_16x16x32_bf16(af[r], bN[c], acc[r][c][1], 0, 0, 0);
                }
        }
        #pragma unroll
        for (int r = 0; r < 4; ++r)
            #pragma unroll
            for (int c = 0; c < 2; ++c) {
                int col = colbase + c * 16 + lrow;
                float bv = bias[col];
                #pragma unroll
                for (int q = 0; q < 4; ++q) {
                    int n = br + r * 16 + kg * 4 + q;
                    if (n < N) {
                        Ab[(size_t)n * 128 + col] = f2bf(acc[r][c][0][q] + bv);
                        T8[(size_t)n * 128 + col] = f2fp8(acc[r][c][1][q]);
                    }
                }
            }
    }
}

// ---------- K3: per-bucket CSR finalize; csr = uint-index offsets (src<<5) ----------
__global__ __launch_bounds__(256) void k_bucket_csr(const unsigned* __restrict__ bsorted,
                                                    const int* __restrict__ bcursor,
                                                    int2* __restrict__ rbe,
                                                    float* __restrict__ dinv,
                                                    int* __restrict__ csr, int N) {
    __shared__ int sh[256];
    __shared__ int cur[256];
    int tid = threadIdx.x;
    int b = blockIdx.x;
    int lo = b * CAP;
    int hi = lo + bcursor[b];
    sh[tid] = 0;
    __syncthreads();
    for (int i = lo + tid; i < hi; i += 256) atomicAdd(&sh[(bsorted[i] >> 16) & 255], 1);
    __syncthreads();
    int v = sh[tid];
    __syncthreads();
    sh[tid] = v;
    __syncthreads();
    for (int off = 1; off < 256; off <<= 1) {
        int t = (tid >= off) ? sh[tid - off] : 0;
        __syncthreads();
        sh[tid] += t;
        __syncthreads();
    }
    int excl = sh[tid] - v;
    int d = (b << 8) + tid;
    if (d < N) {
        rbe[d] = make_int2(lo + excl, lo + excl + v);
        dinv[d] = 1.0f / (float)(v > 1 ? v : 1);
    }
    cur[tid] = lo + excl;
    __syncthreads();
    for (int i = lo + tid; i < hi; i += 256) {
        unsigned pk = bsorted[i];
        int p = atomicAdd(&cur[(pk >> 16) & 255], 1);
        csr[p] = (int)(pk & 0xffffu) << 5;    // uint index of row base (128 B / 4)
    }
}

// ---------- MFMA dual GEMM, bf16 input: Ab = bf16(X@Ws+b), T8 = fp8(X@Wn) ----------
__global__ __launch_bounds__(256) void k_mfma_dual(
    const unsigned short* __restrict__ Xin,
    const unsigned short* __restrict__ WsT, const unsigned short* __restrict__ WnT,
    const float* __restrict__ bias, unsigned short* __restrict__ Ab,
    unsigned char* __restrict__ T8, int N) {
    __shared__ unsigned short xs[64][136];
    int tid = threadIdx.x;
    int br = blockIdx.x << 6;
    #pragma unroll
    for (int it = 0; it < 4; ++it) {
        int idx = tid + it * 256;
        int row = idx >> 4;
        int co = (idx & 15) << 3;
        int n = br + row;
        uint4 pk = make_uint4(0, 0, 0, 0);
        if (n < N) pk = *(const uint4*)(Xin + (size_t)n * 128 + co);
        *(uint4*)&xs[row][co] = pk;
    }
    __syncthreads();
    int wave = tid >> 6;
    int lane = tid & 63;
    int lrow = lane & 15;
    int kg = lane >> 4;
    int colbase = wave << 5;
    f32x4 acc[4][2][2];
    #pragma unroll
    for (int r = 0; r < 4; ++r)
        #pragma unroll
        for (int c = 0; c < 2; ++c) {
            acc[r][c][0] = (f32x4){0.f, 0.f, 0.f, 0.f};
            acc[r][c][1] = (f32x4){0.f, 0.f, 0.f, 0.f};
        }
    #pragma unroll
    for (int ks = 0; ks < 4; ++ks) {
        int kb = ks * 32 + kg * 8;
        bf16x8 af[4];
        #pragma unroll
        for (int r = 0; r < 4; ++r) af[r] = *(const bf16x8*)&xs[r * 16 + lrow][kb];
        bf16x8 bS[2], bN[2];
        #pragma unroll
        for (int c = 0; c < 2; ++c) {
            int col = colbase + c * 16 + lrow;
            bS[c] = *(const bf16x8*)(WsT + (size_t)col * 128 + kb);
            bN[c] = *(const bf16x8*)(WnT + (size_t)col * 128 + kb);
        }
        #pragma unroll
        for (int r = 0; r < 4; ++r)
            #pragma unroll
            for (int c = 0; c < 2; ++c) {
                acc[r][c][0] = __builtin_amdgcn_mfma_f32_16x16x32_bf16(af[r], bS[c], acc[r][c][0], 0, 0, 0);
                acc[r][c][1] = __builtin_amdgcn_mfma_f32_16x16x32_bf16(af[r], bN[c], acc[r][c][1], 0, 0, 0);
            }
    }
    #pragma unroll
    for (int r = 0; r < 4; ++r)
        #pragma unroll
        for (int c = 0; c < 2; ++c) {
            int col = colbase + c * 16 + lrow;
            float bv = bias[col];
            #pragma unroll
            for (int q = 0; q < 4; ++q) {
                int n = br + r * 16 + kg * 4 + q;
                if (n < N) {
                    Ab[(size_t)n * 128 + col] = f2bf(acc[r][c][0][q] + bv);
                    T8[(size_t)n * 128 + col] = f2fp8(acc[r][c][1][q]);
                }
            }
        }
}

// ---------- agg layers 0/1: 2 nodes/wave, 32 lanes x uint per edge ----------
__global__ __launch_bounds__(256) void k_agg_relu(
    const unsigned* __restrict__ T4, const unsigned* __restrict__ Av,
    const float* __restrict__ dinv, const int2* __restrict__ rbe,
    const int* __restrict__ csr, unsigned* __restrict__ Hv, int N) {
    int wave = (blockIdx.x * 256 + threadIdx.x) >> 6;
    int half = (threadIdx.x >> 5) & 1;
    int sl = threadIdx.x & 31;
    int w = wave * 2 + half;
    if (w >= N) return;
    int2 be = rbe[w];
    int e = be.x, ee = be.y;
    float a0 = 0.f, a1 = 0.f, a2 = 0.f, a3 = 0.f;
    for (; e + 8 <= ee; e += 8) {
        int o[8];
        #pragma unroll
        for (int j = 0; j < 8; ++j) o[j] = csr[e + j];
        unsigned v[8];
        #pragma unroll
        for (int j = 0; j < 8; ++j) v[j] = T4[(size_t)o[j] + sl];
        #pragma unroll
        for (int j = 0; j < 8; ++j) {
            f32x2 dlo = __builtin_amdgcn_cvt_pk_f32_fp8(v[j], false);
            f32x2 dhi = __builtin_amdgcn_cvt_pk_f32_fp8(v[j], true);
            a0 += dlo.x; a1 += dlo.y; a2 += dhi.x; a3 += dhi.y;
        }
    }
    for (; e < ee; ++e) {
        unsigned v = T4[(size_t)csr[e] + sl];
        f32x2 dlo = __builtin_amdgcn_cvt_pk_f32_fp8(v, false);
        f32x2 dhi = __builtin_amdgcn_cvt_pk_f32_fp8(v, true);
        a0 += dlo.x; a1 += dlo.y; a2 += dhi.x; a3 += dhi.y;
    }
    float di = dinv[w];
    uint2 av = *(const uint2*)(Av + (size_t)w * 64 + 2 * sl);
    float o0 = fmaxf(bf2f(av.x & 0xffff) + a0 * di, 0.f);
    float o1 = fmaxf(bf2f(av.x >> 16)    + a1 * di, 0.f);
    float o2 = fmaxf(bf2f(av.y & 0xffff) + a2 * di, 0.f);
    float o3 = fmaxf(bf2f(av.y >> 16)    + a3 * di, 0.f);
    uint2 pk;
    pk.x = (unsigned)f2bf(o0) | ((unsigned)f2bf(o1) << 16);
    pk.y = (unsigned)f2bf(o2) | ((unsigned)f2bf(o3) << 16);
    *(uint2*)(Hv + (size_t)w * 64 + 2 * sl) = pk;
}

// ---------- layer-2 MFMA: self sums -> Sb (bf16 pairs), neighbor pairs -> T8 (fp8 pairs) ----------
__global__ __launch_bounds__(256) void k_mfma_layer2(
    const unsigned short* __restrict__ Hb, const float* __restrict__ NZ,
    const unsigned short* __restrict__ WTcat, const float* __restrict__ b2,
    unsigned short* __restrict__ Sb, unsigned short* __restrict__ T8p, int N) {
    __shared__ unsigned short xh[64][136];
    __shared__ unsigned short xz[64][136];
    int tid = threadIdx.x;
    int br = blockIdx.x << 6;
    #pragma unroll
    for (int it = 0; it < 4; ++it) {
        int idx = tid + it * 256;
        int row = idx >> 4;
        int co = (idx & 15) << 3;
        int n = br + row;
        uint4 ph = make_uint4(0, 0, 0, 0), pz = make_uint4(0, 0, 0, 0);
        if (n < N) {
            ph = *(const uint4*)(Hb + (size_t)n * 128 + co);
            float4 v0 = *(const float4*)(NZ + (size_t)n * 128 + co);
            float4 v1 = *(const float4*)(NZ + (size_t)n * 128 + co + 4);
            pz.x = (unsigned)f2bf(v0.x) | ((unsigned)f2bf(v0.y) << 16);
            pz.y = (unsigned)f2bf(v0.z) | ((unsigned)f2bf(v0.w) << 16);
            pz.z = (unsigned)f2bf(v1.x) | ((unsigned)f2bf(v1.y) << 16);
            pz.w = (unsigned)f2bf(v1.z) | ((unsigned)f2bf(v1.w) << 16);
        }
        *(uint4*)&xh[row][co] = ph;
        *(uint4*)&xz[row][co] = pz;
    }
    __syncthreads();
    int wave = tid >> 6;
    int lane = tid & 63;
    int lrow = lane & 15;
    int kg = lane >> 4;
    int colbase = wave << 5;
    f32x4 acc[4][2][2];
    #pragma unroll
    for (int r = 0; r < 4; ++r)
        #pragma unroll
        for (int c = 0; c < 2; ++c) {
            acc[r][c][0] = (f32x4){0.f, 0.f, 0.f, 0.f};
            acc[r][c][1] = (f32x4){0.f, 0.f, 0.f, 0.f};
        }
    #pragma unroll
    for (int ks = 0; ks < 4; ++ks) {
        int kb = ks * 32 + kg * 8;
        bf16x8 ah[4], az[4];
        #pragma unroll
        for (int r = 0; r < 4; ++r) {
            ah[r] = *(const bf16x8*)&xh[r * 16 + lrow][kb];
            az[r] = *(const bf16x8*)&xz[r * 16 + lrow][kb];
        }
        bf16x8 bw[2];
        #pragma unroll
        for (int c = 0; c < 2; ++c) {
            int col = colbase + c * 16 + lrow;
            bw[c] = *(const bf16x8*)(WTcat + (size_t)col * 128 + kb);
        }
        #pragma unroll
        for (int r = 0; r < 4; ++r)
            #pragma unroll
            for (int c = 0; c < 2; ++c) {
                acc[r][c][0] = __builtin_amdgcn_mfma_f32_16x16x32_bf16(ah[r], bw[c], acc[r][c][0], 0, 0, 0);
                acc[r][c][1] = __builtin_amdgcn_mfma_f32_16x16x32_bf16(az[r], bw[c], acc[r][c][1], 0, 0, 0);
            }
    }
    if (wave < 2) {
        #pragma unroll
        for (int r = 0; r < 4; ++r)
            #pragma unroll
            for (int c = 0; c < 2; ++c) {
                int j = colbase + c * 16 + lrow;
                float bv = b2[j];
                #pragma unroll
                for (int q = 0; q < 4; ++q) {
                    int n = br + r * 16 + kg * 4 + q;
                    if (n < N) {
                        float hs = acc[r][c][0][q] + bv;
                        float zs = acc[r][c][1][q];
                        unsigned pk = (unsigned)f2bf(hs) | ((unsigned)f2bf(hs + zs) << 16);
                        ((unsigned*)Sb)[(size_t)n * 64 + j] = pk;
                    }
                }
            }
    } else {
        #pragma unroll
        for (int r = 0; r < 4; ++r)
            #pragma unroll
            for (int c = 0; c < 2; ++c) {
                int j = colbase - 64 + c * 16 + lrow;
                #pragma unroll
                for (int q = 0; q < 4; ++q) {
                    int n = br + r * 16 + kg * 4 + q;
                    if (n < N) {
                        unsigned pk = __builtin_amdgcn_cvt_pk_fp8_f32(
                            acc[r][c][0][q], acc[r][c][1][q], 0, false);
                        T8p[(size_t)n * 64 + j] = (unsigned short)(pk & 0xffffu);
                    }
                }
            }
    }
}

// ---------- layer-2 aggregation: 2 nodes/wave, 32 lanes x uint (2 fp8 pairs) per edge ----------
__global__ __launch_bounds__(256) void k_agg_final2(
    const unsigned* __restrict__ T4, const unsigned* __restrict__ Sv,
    const float* __restrict__ dinv, const int2* __restrict__ rbe,
    const int* __restrict__ csr, float* __restrict__ out, int N) {
    int wave = (blockIdx.x * 256 + threadIdx.x) >> 6;
    int half = (threadIdx.x >> 5) & 1;
    int sl = threadIdx.x & 31;
    int w = wave * 2 + half;
    if (w >= N) return;
    int2 be = rbe[w];
    int e = be.x, ee = be.y;
    float h0 = 0.f, z0 = 0.f, h1 = 0.f, z1 = 0.f;
    for (; e + 8 <= ee; e += 8) {
        int o[8];
        #pragma unroll
        for (int j = 0; j < 8; ++j) o[j] = csr[e + j];
        unsigned v[8];
        #pragma unroll
        for (int j = 0; j < 8; ++j) v[j] = T4[(size_t)o[j] + sl];
        #pragma unroll
        for (int j = 0; j < 8; ++j) {
            f32x2 dlo = __builtin_amdgcn_cvt_pk_f32_fp8(v[j], false);
            f32x2 dhi = __builtin_amdgcn_cvt_pk_f32_fp8(v[j], true);
            h0 += dlo.x; z0 += dlo.y; h1 += dhi.x; z1 += dhi.y;
        }
    }
    for (; e < ee; ++e) {
        unsigned v = T4[(size_t)csr[e] + sl];
        f32x2 dlo = __builtin_amdgcn_cvt_pk_f32_fp8(v, false);
        f32x2 dhi = __builtin_amdgcn_cvt_pk_f32_fp8(v, true);
        h0 += dlo.x; z0 += dlo.y; h1 += dhi.x; z1 += dhi.y;
    }
    float di = dinv[w];
    uint2 sv = *(const uint2*)(Sv + (size_t)w * 64 + 2 * sl);
    float* orow = out + (size_t)w * 128;
    int j0 = 2 * sl;
    float2 hi2 = { bf2f(sv.x & 0xffff) + h0 * di, bf2f(sv.y & 0xffff) + h1 * di };
    float2 lo2 = { bf2f(sv.x >> 16) + (h0 + z0) * di, bf2f(sv.y >> 16) + (h1 + z1) * di };
    *(float2*)(orow + 64 + j0) = hi2;   // h2 cols j0, j0+1
    *(float2*)(orow + j0) = lo2;        // hn2 cols j0, j0+1
}

extern "C" void kernel_launch(void* const* d_in, const int* in_sizes, int n_in,
                              void* d_out, int out_size, void* d_ws, size_t ws_size,
                              hipStream_t stream) {
    const float* features = (const float*)d_in[0];
    const float* noise    = (const float*)d_in[1];
    const float* Ws0 = (const float*)d_in[2];
    const float* Wn0 = (const float*)d_in[3];
    const float* b0  = (const float*)d_in[4];
    const float* Ws1 = (const float*)d_in[5];
    const float* Wn1 = (const float*)d_in[6];
    const float* b1  = (const float*)d_in[7];
    const float* Ws2 = (const float*)d_in[8];
    const float* Wn2 = (const float*)d_in[9];
    const float* b2  = (const float*)d_in[10];
    const int* esrc = (const int*)d_in[11];
    const int* edst = (const int*)d_in[12];
    int N = in_sizes[0] / 128;
    int E = in_sizes[11];
    float* out = (float*)d_out;

    // workspace
    unsigned short* Ab = (unsigned short*)d_ws;            // [N][128] bf16
    unsigned short* Hb = Ab + (size_t)N * 128;             // [N][128] bf16
    unsigned short* Sb = Hb + (size_t)N * 128;             // [N][64] bf16 pairs
    unsigned char*  T8 = (unsigned char*)(Sb + (size_t)N * 128); // [N][128] fp8 / [N][64] pairs
    unsigned short* WT0s = (unsigned short*)(T8 + (size_t)N * 128);
    unsigned short* WT0n = WT0s + 128 * 128;
    unsigned short* WT1s = WT0n + 128 * 128;
    unsigned short* WT1n = WT1s + 128 * 128;
    unsigned short* WT2  = WT1n + 128 * 128;
    float* dinv = (float*)(WT2 + 128 * 128);               // [N]
    int2* rbe  = (int2*)(dinv + N);                        // [N]
    int* csr   = (int*)(rbe + N);                          // [256*CAP]
    unsigned* bsorted = (unsigned*)(csr + 256 * CAP);      // [256*CAP]
    int* bcursor = (int*)(bsorted + 256 * CAP);            // [256]

    int nbk = (N + 255) >> 8;
    int ech = (E + CHUNK - 1) / CHUNK;
    int g64 = (N + 63) / 64;

    k_wt<<<320, 256, 0, stream>>>(Ws0, Wn0, Ws1, Wn1, Ws2, Wn2,
                                  WT0s, WT0n, WT1s, WT1n, WT2, bcursor);
    k_scatter_gemm0<<<ech + g64, 256, 0, stream>>>(esrc, edst, bcursor, bsorted, E, ech,
                                                   features, WT0s, WT0n, b0, Ab, T8, N);
    k_bucket_csr<<<nbk, 256, 0, stream>>>(bsorted, bcursor, rbe, dinv, csr, N);

    int nwaves = (N + 1) / 2;
    int ablocks = (nwaves * 64 + 255) / 256;

    k_agg_relu<<<ablocks, 256, 0, stream>>>((const unsigned*)T8, (const unsigned*)Ab,
                                            dinv, rbe, csr, (unsigned*)Hb, N);
    k_mfma_dual<<<g64, 256, 0, stream>>>(Hb, WT1s, WT1n, b1, Ab, T8, N);
    k_agg_relu<<<ablocks, 256, 0, stream>>>((const unsigned*)T8, (const unsigned*)Ab,
                                            dinv, rbe, csr, (unsigned*)Hb, N);
    k_mfma_layer2<<<g64, 256, 0, stream>>>(Hb, noise, WT2, b2, Sb, (unsigned short*)T8, N);
    k_agg_final2<<<ablocks, 256, 0, stream>>>((const unsigned*)T8, (const unsigned*)Sb,
                                              dinv, rbe, csr, out, N);
}

// Round 17
// 164.027 us; speedup vs baseline: 1.6816x; 1.0339x over previous
//
#include <hip/hip_runtime.h>

typedef __attribute__((ext_vector_type(8))) short bf16x8;
typedef __attribute__((ext_vector_type(4))) float f32x4;
typedef __attribute__((ext_vector_type(2))) float f32x2;

__device__ __forceinline__ unsigned short f2bf(float x) {
    union { float f; unsigned u; } v; v.f = x;
    unsigned r = v.u + 0x7FFFu + ((v.u >> 16) & 1u);
    return (unsigned short)(r >> 16);
}
__device__ __forceinline__ float bf2f(unsigned u) {
    union { unsigned u; float f; } v; v.u = u << 16;
    return v.f;
}
__device__ __forceinline__ unsigned char f2fp8(float x) {
    return (unsigned char)(__builtin_amdgcn_cvt_pk_fp8_f32(x, x, 0, false) & 0xff);
}

#define CHUNK 4096
#define CAP 4608

// ---------- K1: weight transpose + zero bcursor ----------
__global__ __launch_bounds__(256) void k_wt(
    const float* __restrict__ Ws0, const float* __restrict__ Wn0,
    const float* __restrict__ Ws1, const float* __restrict__ Wn1,
    const float* __restrict__ Ws2, const float* __restrict__ Wn2,
    unsigned short* __restrict__ WT0s, unsigned short* __restrict__ WT0n,
    unsigned short* __restrict__ WT1s, unsigned short* __restrict__ WT1n,
    unsigned short* __restrict__ WT2, int* __restrict__ bcursor) {
    int tid = threadIdx.x;
    if (blockIdx.x == 0) bcursor[tid] = 0;
    int i = blockIdx.x * 256 + tid;
    if (i < 16384)      { int j = i;         WT0s[j] = f2bf(Ws0[(j & 127) * 128 + (j >> 7)]); }
    else if (i < 32768) { int j = i - 16384; WT0n[j] = f2bf(Wn0[(j & 127) * 128 + (j >> 7)]); }
    else if (i < 49152) { int j = i - 32768; WT1s[j] = f2bf(Ws1[(j & 127) * 128 + (j >> 7)]); }
    else if (i < 65536) { int j = i - 49152; WT1n[j] = f2bf(Wn1[(j & 127) * 128 + (j >> 7)]); }
    else if (i < 73728) { int j = i - 65536; WT2[j] = f2bf(Ws2[(j & 127) * 64 + (j >> 7)]); }
    else if (i < 81920) { int j = i - 73728; WT2[8192 + j] = f2bf(Wn2[(j & 127) * 64 + (j >> 7)]); }
}

// ---------- K2: bucket scatter (blocks < ech) UNION layer-0 GEMM ----------
__global__ __launch_bounds__(256) void k_scatter_gemm0(
    const int* __restrict__ esrc, const int* __restrict__ edst,
    int* __restrict__ bcursor, unsigned* __restrict__ bsorted, int E, int ech,
    const float* __restrict__ Xf,
    const unsigned short* __restrict__ WsT, const unsigned short* __restrict__ WnT,
    const float* __restrict__ bias, unsigned short* __restrict__ Ab,
    unsigned char* __restrict__ T8, int N) {
    __shared__ uint4 smem[1216];
    int tid = threadIdx.x;
    if ((int)blockIdx.x < ech) {
        unsigned* stage = (unsigned*)smem;
        int* hist = (int*)(stage + CHUNK);
        int* base = hist + 256;
        int* cur  = base + 256;
        hist[tid] = 0;
        __syncthreads();
        int e0 = blockIdx.x * CHUNK;
        int cnt = min(CHUNK, E - e0);
        for (int i = tid; i < cnt; i += 256) {
            int d = edst[e0 + i], s = esrc[e0 + i];
            stage[i] = ((unsigned)d << 16) | (unsigned)s;
            atomicAdd(&hist[d >> 8], 1);
        }
        __syncthreads();
        int h = hist[tid];
        base[tid] = h ? (tid * CAP + atomicAdd(&bcursor[tid], h)) : 0;
        cur[tid] = 0;
        __syncthreads();
        for (int i = tid; i < cnt; i += 256) {
            unsigned pk = stage[i];
            int b = pk >> 24;
            int p = base[b] + atomicAdd(&cur[b], 1);
            bsorted[p] = pk;
        }
    } else {
        unsigned short (*xs)[136] = (unsigned short(*)[136])smem;
        int br = (blockIdx.x - ech) << 6;
        #pragma unroll
        for (int it = 0; it < 4; ++it) {
            int idx = tid + it * 256;
            int row = idx >> 4;
            int co = (idx & 15) << 3;
            int n = br + row;
            uint4 pk = make_uint4(0, 0, 0, 0);
            if (n < N) {
                float4 v0 = *(const float4*)(Xf + (size_t)n * 128 + co);
                float4 v1 = *(const float4*)(Xf + (size_t)n * 128 + co + 4);
                pk.x = (unsigned)f2bf(v0.x) | ((unsigned)f2bf(v0.y) << 16);
                pk.y = (unsigned)f2bf(v0.z) | ((unsigned)f2bf(v0.w) << 16);
                pk.z = (unsigned)f2bf(v1.x) | ((unsigned)f2bf(v1.y) << 16);
                pk.w = (unsigned)f2bf(v1.z) | ((unsigned)f2bf(v1.w) << 16);
            }
            *(uint4*)&xs[row][co] = pk;
        }
        __syncthreads();
        int wave = tid >> 6;
        int lane = tid & 63;
        int lrow = lane & 15;
        int kg = lane >> 4;
        int colbase = wave << 5;
        f32x4 acc[4][2][2];
        #pragma unroll
        for (int r = 0; r < 4; ++r)
            #pragma unroll
            for (int c = 0; c < 2; ++c) {
                acc[r][c][0] = (f32x4){0.f, 0.f, 0.f, 0.f};
                acc[r][c][1] = (f32x4){0.f, 0.f, 0.f, 0.f};
            }
        #pragma unroll
        for (int ks = 0; ks < 4; ++ks) {
            int kb = ks * 32 + kg * 8;
            bf16x8 af[4];
            #pragma unroll
            for (int r = 0; r < 4; ++r) af[r] = *(const bf16x8*)&xs[r * 16 + lrow][kb];
            bf16x8 bS[2], bN[2];
            #pragma unroll
            for (int c = 0; c < 2; ++c) {
                int col = colbase + c * 16 + lrow;
                bS[c] = *(const bf16x8*)(WsT + (size_t)col * 128 + kb);
                bN[c] = *(const bf16x8*)(WnT + (size_t)col * 128 + kb);
            }
            #pragma unroll
            for (int r = 0; r < 4; ++r)
                #pragma unroll
                for (int c = 0; c < 2; ++c) {
                    acc[r][c][0] = __builtin_amdgcn_mfma_f32_16x16x32_bf16(af[r], bS[c], acc[r][c][0], 0, 0, 0);
                    acc[r][c][1] = __builtin_amdgcn_mfma_f32_16x16x32_bf16(af[r], bN[c], acc[r][c][1], 0, 0, 0);
                }
        }
        #pragma unroll
        for (int r = 0; r < 4; ++r)
            #pragma unroll
            for (int c = 0; c < 2; ++c) {
                int col = colbase + c * 16 + lrow;
                float bv = bias[col];
                #pragma unroll
                for (int q = 0; q < 4; ++q) {
                    int n = br + r * 16 + kg * 4 + q;
                    if (n < N) {
                        Ab[(size_t)n * 128 + col] = f2bf(acc[r][c][0][q] + bv);
                        T8[(size_t)n * 128 + col] = f2fp8(acc[r][c][1][q]);
                    }
                }
            }
    }
}

// ---------- K3: per-bucket CSR finalize; csr = uint2-index offsets (src<<4) ----------
__global__ __launch_bounds__(256) void k_bucket_csr(const unsigned* __restrict__ bsorted,
                                                    const int* __restrict__ bcursor,
                                                    int2* __restrict__ rbe,
                                                    float* __restrict__ dinv,
                                                    int* __restrict__ csr, int N) {
    __shared__ int sh[256];
    __shared__ int cur[256];
    int tid = threadIdx.x;
    int b = blockIdx.x;
    int lo = b * CAP;
    int hi = lo + bcursor[b];
    sh[tid] = 0;
    __syncthreads();
    for (int i = lo + tid; i < hi; i += 256) atomicAdd(&sh[(bsorted[i] >> 16) & 255], 1);
    __syncthreads();
    int v = sh[tid];
    __syncthreads();
    sh[tid] = v;
    __syncthreads();
    for (int off = 1; off < 256; off <<= 1) {
        int t = (tid >= off) ? sh[tid - off] : 0;
        __syncthreads();
        sh[tid] += t;
        __syncthreads();
    }
    int excl = sh[tid] - v;
    int d = (b << 8) + tid;
    if (d < N) {
        rbe[d] = make_int2(lo + excl, lo + excl + v);
        dinv[d] = 1.0f / (float)(v > 1 ? v : 1);
    }
    cur[tid] = lo + excl;
    __syncthreads();
    for (int i = lo + tid; i < hi; i += 256) {
        unsigned pk = bsorted[i];
        int p = atomicAdd(&cur[(pk >> 16) & 255], 1);
        csr[p] = (int)(pk & 0xffffu) << 4;    // uint2 index of 128B row base
    }
}

// ---------- MFMA dual GEMM, bf16 input: Ab = bf16(X@Ws+b), T8 = fp8(X@Wn) ----------
__global__ __launch_bounds__(256) void k_mfma_dual(
    const unsigned short* __restrict__ Xin,
    const unsigned short* __restrict__ WsT, const unsigned short* __restrict__ WnT,
    const float* __restrict__ bias, unsigned short* __restrict__ Ab,
    unsigned char* __restrict__ T8, int N) {
    __shared__ unsigned short xs[64][136];
    int tid = threadIdx.x;
    int br = blockIdx.x << 6;
    #pragma unroll
    for (int it = 0; it < 4; ++it) {
        int idx = tid + it * 256;
        int row = idx >> 4;
        int co = (idx & 15) << 3;
        int n = br + row;
        uint4 pk = make_uint4(0, 0, 0, 0);
        if (n < N) pk = *(const uint4*)(Xin + (size_t)n * 128 + co);
        *(uint4*)&xs[row][co] = pk;
    }
    __syncthreads();
    int wave = tid >> 6;
    int lane = tid & 63;
    int lrow = lane & 15;
    int kg = lane >> 4;
    int colbase = wave << 5;
    f32x4 acc[4][2][2];
    #pragma unroll
    for (int r = 0; r < 4; ++r)
        #pragma unroll
        for (int c = 0; c < 2; ++c) {
            acc[r][c][0] = (f32x4){0.f, 0.f, 0.f, 0.f};
            acc[r][c][1] = (f32x4){0.f, 0.f, 0.f, 0.f};
        }
    #pragma unroll
    for (int ks = 0; ks < 4; ++ks) {
        int kb = ks * 32 + kg * 8;
        bf16x8 af[4];
        #pragma unroll
        for (int r = 0; r < 4; ++r) af[r] = *(const bf16x8*)&xs[r * 16 + lrow][kb];
        bf16x8 bS[2], bN[2];
        #pragma unroll
        for (int c = 0; c < 2; ++c) {
            int col = colbase + c * 16 + lrow;
            bS[c] = *(const bf16x8*)(WsT + (size_t)col * 128 + kb);
            bN[c] = *(const bf16x8*)(WnT + (size_t)col * 128 + kb);
        }
        #pragma unroll
        for (int r = 0; r < 4; ++r)
            #pragma unroll
            for (int c = 0; c < 2; ++c) {
                acc[r][c][0] = __builtin_amdgcn_mfma_f32_16x16x32_bf16(af[r], bS[c], acc[r][c][0], 0, 0, 0);
                acc[r][c][1] = __builtin_amdgcn_mfma_f32_16x16x32_bf16(af[r], bN[c], acc[r][c][1], 0, 0, 0);
            }
    }
    #pragma unroll
    for (int r = 0; r < 4; ++r)
        #pragma unroll
        for (int c = 0; c < 2; ++c) {
            int col = colbase + c * 16 + lrow;
            float bv = bias[col];
            #pragma unroll
            for (int q = 0; q < 4; ++q) {
                int n = br + r * 16 + kg * 4 + q;
                if (n < N) {
                    Ab[(size_t)n * 128 + col] = f2bf(acc[r][c][0][q] + bv);
                    T8[(size_t)n * 128 + col] = f2fp8(acc[r][c][1][q]);
                }
            }
        }
}

// ---------- agg layers 0/1: 4 nodes/wave, 16 lanes x uint2 per edge ----------
__global__ __launch_bounds__(256) void k_agg_relu(
    const uint2* __restrict__ T2, const uint4* __restrict__ Av4,
    const float* __restrict__ dinv, const int2* __restrict__ rbe,
    const int* __restrict__ csr, uint4* __restrict__ Hv4, int N) {
    int wave = (blockIdx.x * 256 + threadIdx.x) >> 6;
    int quarter = (threadIdx.x >> 4) & 3;
    int sl = threadIdx.x & 15;
    int w = wave * 4 + quarter;
    if (w >= N) return;
    int2 be = rbe[w];
    int e = be.x, ee = be.y;
    float a0 = 0.f, a1 = 0.f, a2 = 0.f, a3 = 0.f;
    float a4 = 0.f, a5 = 0.f, a6 = 0.f, a7 = 0.f;
    for (; e + 8 <= ee; e += 8) {
        int o[8];
        #pragma unroll
        for (int j = 0; j < 8; ++j) o[j] = csr[e + j];
        uint2 v[8];
        #pragma unroll
        for (int j = 0; j < 8; ++j) v[j] = T2[(size_t)o[j] + sl];
        #pragma unroll
        for (int j = 0; j < 8; ++j) {
            f32x2 d0 = __builtin_amdgcn_cvt_pk_f32_fp8(v[j].x, false);
            f32x2 d1 = __builtin_amdgcn_cvt_pk_f32_fp8(v[j].x, true);
            f32x2 d2 = __builtin_amdgcn_cvt_pk_f32_fp8(v[j].y, false);
            f32x2 d3 = __builtin_amdgcn_cvt_pk_f32_fp8(v[j].y, true);
            a0 += d0.x; a1 += d0.y; a2 += d1.x; a3 += d1.y;
            a4 += d2.x; a5 += d2.y; a6 += d3.x; a7 += d3.y;
        }
    }
    for (; e < ee; ++e) {
        uint2 v = T2[(size_t)csr[e] + sl];
        f32x2 d0 = __builtin_amdgcn_cvt_pk_f32_fp8(v.x, false);
        f32x2 d1 = __builtin_amdgcn_cvt_pk_f32_fp8(v.x, true);
        f32x2 d2 = __builtin_amdgcn_cvt_pk_f32_fp8(v.y, false);
        f32x2 d3 = __builtin_amdgcn_cvt_pk_f32_fp8(v.y, true);
        a0 += d0.x; a1 += d0.y; a2 += d1.x; a3 += d1.y;
        a4 += d2.x; a5 += d2.y; a6 += d3.x; a7 += d3.y;
    }
    float di = dinv[w];
    uint4 av = Av4[(size_t)w * 16 + sl];
    uint4 pk;
    {
        float o0 = fmaxf(bf2f(av.x & 0xffff) + a0 * di, 0.f);
        float o1 = fmaxf(bf2f(av.x >> 16)    + a1 * di, 0.f);
        float o2 = fmaxf(bf2f(av.y & 0xffff) + a2 * di, 0.f);
        float o3 = fmaxf(bf2f(av.y >> 16)    + a3 * di, 0.f);
        float o4 = fmaxf(bf2f(av.z & 0xffff) + a4 * di, 0.f);
        float o5 = fmaxf(bf2f(av.z >> 16)    + a5 * di, 0.f);
        float o6 = fmaxf(bf2f(av.w & 0xffff) + a6 * di, 0.f);
        float o7 = fmaxf(bf2f(av.w >> 16)    + a7 * di, 0.f);
        pk.x = (unsigned)f2bf(o0) | ((unsigned)f2bf(o1) << 16);
        pk.y = (unsigned)f2bf(o2) | ((unsigned)f2bf(o3) << 16);
        pk.z = (unsigned)f2bf(o4) | ((unsigned)f2bf(o5) << 16);
        pk.w = (unsigned)f2bf(o6) | ((unsigned)f2bf(o7) << 16);
    }
    Hv4[(size_t)w * 16 + sl] = pk;
}

// ---------- layer-2 MFMA: self sums -> Sb (bf16 pairs), neighbor pairs -> T8 (fp8 pairs) ----------
__global__ __launch_bounds__(256) void k_mfma_layer2(
    const unsigned short* __restrict__ Hb, const float* __restrict__ NZ,
    const unsigned short* __restrict__ WTcat, const float* __restrict__ b2,
    unsigned short* __restrict__ Sb, unsigned short* __restrict__ T8p, int N) {
    __shared__ unsigned short xh[64][136];
    __shared__ unsigned short xz[64][136];
    int tid = threadIdx.x;
    int br = blockIdx.x << 6;
    #pragma unroll
    for (int it = 0; it < 4; ++it) {
        int idx = tid + it * 256;
        int row = idx >> 4;
        int co = (idx & 15) << 3;
        int n = br + row;
        uint4 ph = make_uint4(0, 0, 0, 0), pz = make_uint4(0, 0, 0, 0);
        if (n < N) {
            ph = *(const uint4*)(Hb + (size_t)n * 128 + co);
            float4 v0 = *(const float4*)(NZ + (size_t)n * 128 + co);
            float4 v1 = *(const float4*)(NZ + (size_t)n * 128 + co + 4);
            pz.x = (unsigned)f2bf(v0.x) | ((unsigned)f2bf(v0.y) << 16);
            pz.y = (unsigned)f2bf(v0.z) | ((unsigned)f2bf(v0.w) << 16);
            pz.z = (unsigned)f2bf(v1.x) | ((unsigned)f2bf(v1.y) << 16);
            pz.w = (unsigned)f2bf(v1.z) | ((unsigned)f2bf(v1.w) << 16);
        }
        *(uint4*)&xh[row][co] = ph;
        *(uint4*)&xz[row][co] = pz;
    }
    __syncthreads();
    int wave = tid >> 6;
    int lane = tid & 63;
    int lrow = lane & 15;
    int kg = lane >> 4;
    int colbase = wave << 5;
    f32x4 acc[4][2][2];
    #pragma unroll
    for (int r = 0; r < 4; ++r)
        #pragma unroll
        for (int c = 0; c < 2; ++c) {
            acc[r][c][0] = (f32x4){0.f, 0.f, 0.f, 0.f};
            acc[r][c][1] = (f32x4){0.f, 0.f, 0.f, 0.f};
        }
    #pragma unroll
    for (int ks = 0; ks < 4; ++ks) {
        int kb = ks * 32 + kg * 8;
        bf16x8 ah[4], az[4];
        #pragma unroll
        for (int r = 0; r < 4; ++r) {
            ah[r] = *(const bf16x8*)&xh[r * 16 + lrow][kb];
            az[r] = *(const bf16x8*)&xz[r * 16 + lrow][kb];
        }
        bf16x8 bw[2];
        #pragma unroll
        for (int c = 0; c < 2; ++c) {
            int col = colbase + c * 16 + lrow;
            bw[c] = *(const bf16x8*)(WTcat + (size_t)col * 128 + kb);
        }
        #pragma unroll
        for (int r = 0; r < 4; ++r)
            #pragma unroll
            for (int c = 0; c < 2; ++c) {
                acc[r][c][0] = __builtin_amdgcn_mfma_f32_16x16x32_bf16(ah[r], bw[c], acc[r][c][0], 0, 0, 0);
                acc[r][c][1] = __builtin_amdgcn_mfma_f32_16x16x32_bf16(az[r], bw[c], acc[r][c][1], 0, 0, 0);
            }
    }
    if (wave < 2) {
        #pragma unroll
        for (int r = 0; r < 4; ++r)
            #pragma unroll
            for (int c = 0; c < 2; ++c) {
                int j = colbase + c * 16 + lrow;
                float bv = b2[j];
                #pragma unroll
                for (int q = 0; q < 4; ++q) {
                    int n = br + r * 16 + kg * 4 + q;
                    if (n < N) {
                        float hs = acc[r][c][0][q] + bv;
                        float zs = acc[r][c][1][q];
                        unsigned pk = (unsigned)f2bf(hs) | ((unsigned)f2bf(hs + zs) << 16);
                        ((unsigned*)Sb)[(size_t)n * 64 + j] = pk;
                    }
                }
            }
    } else {
        #pragma unroll
        for (int r = 0; r < 4; ++r)
            #pragma unroll
            for (int c = 0; c < 2; ++c) {
                int j = colbase - 64 + c * 16 + lrow;
                #pragma unroll
                for (int q = 0; q < 4; ++q) {
                    int n = br + r * 16 + kg * 4 + q;
                    if (n < N) {
                        unsigned pk = __builtin_amdgcn_cvt_pk_fp8_f32(
                            acc[r][c][0][q], acc[r][c][1][q], 0, false);
                        T8p[(size_t)n * 64 + j] = (unsigned short)(pk & 0xffffu);
                    }
                }
            }
    }
}

// ---------- layer-2 aggregation: 4 nodes/wave, 16 lanes x uint2 (4 fp8 pairs) per edge ----------
__global__ __launch_bounds__(256) void k_agg_final2(
    const uint2* __restrict__ T2, const uint4* __restrict__ Sv4,
    const float* __restrict__ dinv, const int2* __restrict__ rbe,
    const int* __restrict__ csr, float* __restrict__ out, int N) {
    int wave = (blockIdx.x * 256 + threadIdx.x) >> 6;
    int quarter = (threadIdx.x >> 4) & 3;
    int sl = threadIdx.x & 15;
    int w = wave * 4 + quarter;
    if (w >= N) return;
    int2 be = rbe[w];
    int e = be.x, ee = be.y;
    float h0 = 0.f, z0 = 0.f, h1 = 0.f, z1 = 0.f;
    float h2 = 0.f, z2 = 0.f, h3 = 0.f, z3 = 0.f;
    for (; e + 8 <= ee; e += 8) {
        int o[8];
        #pragma unroll
        for (int j = 0; j < 8; ++j) o[j] = csr[e + j];
        uint2 v[8];
        #pragma unroll
        for (int j = 0; j < 8; ++j) v[j] = T2[(size_t)o[j] + sl];
        #pragma unroll
        for (int j = 0; j < 8; ++j) {
            f32x2 d0 = __builtin_amdgcn_cvt_pk_f32_fp8(v[j].x, false);
            f32x2 d1 = __builtin_amdgcn_cvt_pk_f32_fp8(v[j].x, true);
            f32x2 d2 = __builtin_amdgcn_cvt_pk_f32_fp8(v[j].y, false);
            f32x2 d3 = __builtin_amdgcn_cvt_pk_f32_fp8(v[j].y, true);
            h0 += d0.x; z0 += d0.y; h1 += d1.x; z1 += d1.y;
            h2 += d2.x; z2 += d2.y; h3 += d3.x; z3 += d3.y;
        }
    }
    for (; e < ee; ++e) {
        uint2 v = T2[(size_t)csr[e] + sl];
        f32x2 d0 = __builtin_amdgcn_cvt_pk_f32_fp8(v.x, false);
        f32x2 d1 = __builtin_amdgcn_cvt_pk_f32_fp8(v.x, true);
        f32x2 d2 = __builtin_amdgcn_cvt_pk_f32_fp8(v.y, false);
        f32x2 d3 = __builtin_amdgcn_cvt_pk_f32_fp8(v.y, true);
        h0 += d0.x; z0 += d0.y; h1 += d1.x; z1 += d1.y;
        h2 += d2.x; z2 += d2.y; h3 += d3.x; z3 += d3.y;
    }
    float di = dinv[w];
    uint4 sv = Sv4[(size_t)w * 16 + sl];
    int j0 = 4 * sl;
    float* orow = out + (size_t)w * 128;
    float4 hi4 = { bf2f(sv.x & 0xffff) + h0 * di,
                   bf2f(sv.y & 0xffff) + h1 * di,
                   bf2f(sv.z & 0xffff) + h2 * di,
                   bf2f(sv.w & 0xffff) + h3 * di };
    float4 lo4 = { bf2f(sv.x >> 16) + (h0 + z0) * di,
                   bf2f(sv.y >> 16) + (h1 + z1) * di,
                   bf2f(sv.z >> 16) + (h2 + z2) * di,
                   bf2f(sv.w >> 16) + (h3 + z3) * di };
    *(float4*)(orow + 64 + j0) = hi4;   // h2 cols j0..j0+3
    *(float4*)(orow + j0) = lo4;        // hn2 cols j0..j0+3
}

extern "C" void kernel_launch(void* const* d_in, const int* in_sizes, int n_in,
                              void* d_out, int out_size, void* d_ws, size_t ws_size,
                              hipStream_t stream) {
    const float* features = (const float*)d_in[0];
    const float* noise    = (const float*)d_in[1];
    const float* Ws0 = (const float*)d_in[2];
    const float* Wn0 = (const float*)d_in[3];
    const float* b0  = (const float*)d_in[4];
    const float* Ws1 = (const float*)d_in[5];
    const float* Wn1 = (const float*)d_in[6];
    const float* b1  = (const float*)d_in[7];
    const float* Ws2 = (const float*)d_in[8];
    const float* Wn2 = (const float*)d_in[9];
    const float* b2  = (const float*)d_in[10];
    const int* esrc = (const int*)d_in[11];
    const int* edst = (const int*)d_in[12];
    int N = in_sizes[0] / 128;
    int E = in_sizes[11];
    float* out = (float*)d_out;

    // workspace
    unsigned short* Ab = (unsigned short*)d_ws;            // [N][128] bf16
    unsigned short* Hb = Ab + (size_t)N * 128;             // [N][128] bf16
    unsigned short* Sb = Hb + (size_t)N * 128;             // [N][64] bf16 pairs
    unsigned char*  T8 = (unsigned char*)(Sb + (size_t)N * 128); // [N][128] fp8 / [N][64] pairs
    unsigned short* WT0s = (unsigned short*)(T8 + (size_t)N * 128);
    unsigned short* WT0n = WT0s + 128 * 128;
    unsigned short* WT1s = WT0n + 128 * 128;
    unsigned short* WT1n = WT1s + 128 * 128;
    unsigned short* WT2  = WT1n + 128 * 128;
    float* dinv = (float*)(WT2 + 128 * 128);               // [N]
    int2* rbe  = (int2*)(dinv + N);                        // [N]
    int* csr   = (int*)(rbe + N);                          // [256*CAP]
    unsigned* bsorted = (unsigned*)(csr + 256 * CAP);      // [256*CAP]
    int* bcursor = (int*)(bsorted + 256 * CAP);            // [256]

    int nbk = (N + 255) >> 8;
    int ech = (E + CHUNK - 1) / CHUNK;
    int g64 = (N + 63) / 64;

    k_wt<<<320, 256, 0, stream>>>(Ws0, Wn0, Ws1, Wn1, Ws2, Wn2,
                                  WT0s, WT0n, WT1s, WT1n, WT2, bcursor);
    k_scatter_gemm0<<<ech + g64, 256, 0, stream>>>(esrc, edst, bcursor, bsorted, E, ech,
                                                   features, WT0s, WT0n, b0, Ab, T8, N);
    k_bucket_csr<<<nbk, 256, 0, stream>>>(bsorted, bcursor, rbe, dinv, csr, N);

    int nwaves = (N + 3) / 4;
    int ablocks = (nwaves * 64 + 255) / 256;

    k_agg_relu<<<ablocks, 256, 0, stream>>>((const uint2*)T8, (const uint4*)Ab,
                                            dinv, rbe, csr, (uint4*)Hb, N);
    k_mfma_dual<<<g64, 256, 0, stream>>>(Hb, WT1s, WT1n, b1, Ab, T8, N);
    k_agg_relu<<<ablocks, 256, 0, stream>>>((const uint2*)T8, (const uint4*)Ab,
                                            dinv, rbe, csr, (uint4*)Hb, N);
    k_mfma_layer2<<<g64, 256, 0, stream>>>(Hb, noise, WT2, b2, Sb, (unsigned short*)T8, N);
    k_agg_final2<<<ablocks, 256, 0, stream>>>((const uint2*)T8, (const uint4*)Sb,
                                              dinv, rbe, csr, out, N);
}